// Round 6
// baseline (1323.736 us; speedup 1.0000x reference)
//
#include <hip/hip_runtime.h>
#include <hip/hip_cooperative_groups.h>

namespace cg = cooperative_groups;

typedef __attribute__((ext_vector_type(8))) short bf16x8;
typedef __attribute__((ext_vector_type(4))) float f32x4;

constexpr float LN_EPS = 1e-5f;

__device__ inline ushort f2bf(float f) {
  uint u = __float_as_uint(f);
  u += 0x7FFF + ((u >> 16) & 1);   // round-to-nearest-even
  return (ushort)(u >> 16);
}
__device__ inline float bflo(uint u) { return __uint_as_float(u << 16); }
__device__ inline float bfhi(uint u) { return __uint_as_float(u & 0xFFFF0000u); }
__device__ inline uint pk2(float lo, float hi) { return (uint)f2bf(lo) | ((uint)f2bf(hi) << 16); }

struct Params {
  const float* x; const int* ei;
  const float *W_ne, *b_ne, *W_l, *b_l, *W_r, *gamma, *beta, *W_lin, *b_lin;
  float* out;
  ushort *Abf, *Qbf, *H1, *Dbf, *xbf, *WAt, *WBt, *Wlt, *Wrt, *Wlint;
  float *bA, *bB;
  int *cnt, *incl, *rowptr, *cursor, *bsums, *srclist;
  int N, E, nbS, nbT;
};

// ================= shared device bodies =================

__device__ __forceinline__ void body_zero_cast(const Params& p, int gt, int nt) {
  for (int i = gt; i < p.N; i += nt) p.cnt[i] = 0;
  const float4* xin = (const float4*)p.x;
  uint4* xo = (uint4*)p.xbf;
  int n16 = p.N * 16;
  for (int i = gt; i < n16; i += nt) {
    float4 a = xin[2 * (size_t)i], b = xin[2 * (size_t)i + 1];
    uint4 v;
    v.x = pk2(a.x, a.y); v.y = pk2(a.z, a.w);
    v.z = pk2(b.x, b.y); v.w = pk2(b.z, b.w);
    xo[i] = v;
  }
}

__device__ __forceinline__ void body_hist(const Params& p, int gt, int nt) {
  for (int e = gt; e < p.E; e += nt) atomicAdd(&p.cnt[p.ei[p.E + e]], 1);
}

__device__ __forceinline__ void body_scan1(const Params& p, int blk, int tid, int* sh) {
  int i = blk * 256 + tid;
  int v = (i < p.N) ? p.cnt[i] : 0;
  sh[tid] = v;
  __syncthreads();
  for (int off = 1; off < 256; off <<= 1) {
    int t = (tid >= off) ? sh[tid - off] : 0;
    __syncthreads();
    sh[tid] += t;
    __syncthreads();
  }
  if (i < p.N) p.incl[i] = sh[tid];
  if (tid == 255) p.bsums[blk] = sh[255];
}

__device__ __forceinline__ void body_scan2(const Params& p, int tid, int* sh) {
  int v = (tid < p.nbS) ? p.bsums[tid] : 0;
  sh[tid] = v;
  __syncthreads();
  for (int off = 1; off < 256; off <<= 1) {
    int t = (tid >= off) ? sh[tid - off] : 0;
    __syncthreads();
    sh[tid] += t;
    __syncthreads();
  }
  if (tid < p.nbS) p.bsums[tid] = sh[tid] - v;  // exclusive
}

__device__ __forceinline__ void body_prep(const Params& p, int blk, int tid, float* srow) {
  const float* src = (blk < 128) ? (p.W_ne + blk * 128) : p.b_ne;
  if (tid < 128) srow[tid] = src[tid];
  __syncthreads();
  int col = tid & 127;
  const float* Wx = (tid < 128) ? p.W_l : p.W_r;
  float acc = 0.f;
#pragma unroll 8
  for (int k = 0; k < 128; ++k) acc = fmaf(srow[k], Wx[k * 128 + col], acc);
  if (blk < 128) {
    ushort* dst = (tid < 128) ? p.WAt : p.WBt;
    dst[col * 128 + blk] = f2bf(acc);
  } else {
    float* dst = (tid < 128) ? p.bA : p.bB;
    dst[col] = acc;
  }
}

__device__ __forceinline__ void body_wcast(const Params& p, int rb, int nb, int tid) {
  int i0 = rb * 256 + tid, st = nb * 256;
  for (int t = i0; t < 16384; t += st) p.Wlt[(t & 127) * 128 + (t >> 7)] = f2bf(p.W_l[t]);
  for (int t = i0; t < 16384; t += st) p.Wrt[(t & 127) * 128 + (t >> 7)] = f2bf(p.W_r[t]);
  for (int t = i0; t < 8192; t += st) p.Wlint[(t & 63) * 128 + (t >> 6)] = f2bf(p.W_lin[t]);
}

__device__ __forceinline__ void body_rowptr(const Params& p, int blk, int tid) {
  int i = blk * 256 + tid;
  if (i < p.N) {
    int inc = p.incl[i] + p.bsums[blk];
    p.rowptr[i + 1] = inc;
    p.cursor[i] = inc - p.cnt[i];
  }
  if (i == 0) p.rowptr[0] = 0;
}

__device__ __forceinline__ void body_fill(const Params& p, int gt, int nt) {
  for (int e = gt; e < p.E; e += nt) {
    int s = p.ei[e], d = p.ei[p.E + e];
    int pos = atomicAdd(&p.cursor[d], 1);
    p.srclist[pos] = s;
  }
}

// -------- no-LDS MFMA GEMM tile: 64 rows x NCOL cols, 4 waves (2x2) --------

template <int NCOL, bool BF16OUT>
__device__ __forceinline__ void gemm_tile(const ushort* __restrict__ X, const ushort* __restrict__ Wt,
                                          const float* __restrict__ bias, void* __restrict__ Yv,
                                          int M, int tile) {
  constexpr int NF = NCOL / 32;
  const int tid = threadIdx.x;
  const int wave = tid >> 6, lane = tid & 63;
  const int rbase = (wave >> 1) * 32;
  const int cbase = (wave & 1) * (NCOL / 2);
  const int lrow = lane & 15, lkb = (lane >> 4) * 8;
  const int row0 = tile * 64;

  size_t rIdx[2];
#pragma unroll
  for (int mf = 0; mf < 2; ++mf) {
    int r = row0 + rbase + mf * 16 + lrow;
    rIdx[mf] = (size_t)((r < M) ? r : (M - 1));
  }

  f32x4 acc[2][NF];
#pragma unroll
  for (int mf = 0; mf < 2; ++mf)
#pragma unroll
    for (int nf = 0; nf < NF; ++nf) acc[mf][nf] = (f32x4){0.f, 0.f, 0.f, 0.f};

#pragma unroll
  for (int ks = 0; ks < 4; ++ks) {
    bf16x8 a[2], b[NF];
#pragma unroll
    for (int mf = 0; mf < 2; ++mf)
      a[mf] = *(const bf16x8*)(X + rIdx[mf] * 128 + ks * 32 + lkb);
#pragma unroll
    for (int nf = 0; nf < NF; ++nf)
      b[nf] = *(const bf16x8*)(Wt + (size_t)(cbase + nf * 16 + lrow) * 128 + ks * 32 + lkb);
#pragma unroll
    for (int mf = 0; mf < 2; ++mf)
#pragma unroll
      for (int nf = 0; nf < NF; ++nf)
        acc[mf][nf] = __builtin_amdgcn_mfma_f32_16x16x32_bf16(a[mf], b[nf], acc[mf][nf], 0, 0, 0);
  }

#pragma unroll
  for (int nf = 0; nf < NF; ++nf) {
    int col = cbase + nf * 16 + lrow;
    float bv = bias ? bias[col] : 0.f;
#pragma unroll
    for (int mf = 0; mf < 2; ++mf) {
      int growb = row0 + rbase + mf * 16 + (lane >> 4) * 4;
#pragma unroll
      for (int r = 0; r < 4; ++r) {
        int grow = growb + r;
        if (grow < M) {
          float val = acc[mf][nf][r] + bv;
          if constexpr (BF16OUT)
            ((ushort*)Yv)[(size_t)grow * NCOL + col] = f2bf(val);
          else
            ((float*)Yv)[(size_t)grow * NCOL + col] = val;
        }
      }
    }
  }
}

__device__ __forceinline__ void gemm_job1(const Params& p, int job) {
  if (job < p.nbT) gemm_tile<128, true>(p.xbf, p.WAt, p.bA, p.Abf, p.N, job);
  else gemm_tile<128, true>(p.xbf, p.WBt, p.bB, p.Qbf, p.N, job - p.nbT);
}
__device__ __forceinline__ void gemm_job2(const Params& p, int job) {
  if (job < p.nbT) gemm_tile<128, true>(p.Dbf, p.Wlt, nullptr, p.Abf, p.N, job);
  else gemm_tile<128, true>(p.Dbf, p.Wrt, nullptr, p.Qbf, p.N, job - p.nbT);
}
__device__ __forceinline__ void gemm_jobO(const Params& p, int job) {
  gemm_tile<64, false>(p.Dbf, p.Wlint, p.b_lin, p.out, p.N, job);
}

// -------- gather/LN (wave per node, 8 edges in flight per iteration) --------

__device__ __forceinline__ void acc8(uint4 u, float* a) {
  a[0] += bflo(u.x); a[1] += bfhi(u.x);
  a[2] += bflo(u.y); a[3] += bfhi(u.y);
  a[4] += bflo(u.z); a[5] += bfhi(u.z);
  a[6] += bflo(u.w); a[7] += bfhi(u.w);
}

__device__ __forceinline__ void gather_mean(const ushort* __restrict__ Pm, const int* __restrict__ rowptr,
                                            const int* __restrict__ srclist, int w, int lane, float* a) {
  const uint4* Pv = (const uint4*)Pm;
  int fl = lane & 15, g4 = lane >> 4;
  int beg = rowptr[w], end = rowptr[w + 1];
  for (int base = beg; base < end; base += 64) {
    int m = end - base;
    if (m > 64) m = 64;
    int sidx = (lane < m) ? srclist[base + lane] : 0;
    for (int i = 0; i < m; i += 8) {
      int j0 = i + g4, j1 = j0 + 4;
      int s0 = __shfl(sidx, j0 & 63, 64);
      int s1 = __shfl(sidx, j1 & 63, 64);
      uint4 z = make_uint4(0u, 0u, 0u, 0u);
      uint4 u0 = (j0 < m) ? Pv[(size_t)s0 * 16 + fl] : z;
      uint4 u1 = (j1 < m) ? Pv[(size_t)s1 * 16 + fl] : z;
      acc8(u0, a);
      acc8(u1, a);
    }
  }
#pragma unroll
  for (int k = 0; k < 8; ++k) {
    a[k] += __shfl_xor(a[k], 16, 64);
    a[k] += __shfl_xor(a[k], 32, 64);
  }
  float inv = 1.f / fmaxf((float)(end - beg), 1.f);
#pragma unroll
  for (int k = 0; k < 8; ++k) a[k] *= inv;
}

__device__ __forceinline__ void ln_relu8(const float* h, const float* __restrict__ gamma,
                                         const float* __restrict__ beta, int fl, float* o) {
  float sum = 0.f;
#pragma unroll
  for (int k = 0; k < 8; ++k) sum += h[k];
#pragma unroll
  for (int off = 1; off < 16; off <<= 1) sum += __shfl_xor(sum, off, 64);
  float mu = sum * (1.f / 128.f);
  float s2 = 0.f;
#pragma unroll
  for (int k = 0; k < 8; ++k) { float d = h[k] - mu; s2 += d * d; }
#pragma unroll
  for (int off = 1; off < 16; off <<= 1) s2 += __shfl_xor(s2, off, 64);
  float scale = rsqrtf(s2 * (1.f / 128.f) + LN_EPS);
  float4 g0 = *(const float4*)(gamma + fl * 8);
  float4 g1 = *(const float4*)(gamma + fl * 8 + 4);
  float4 b0 = *(const float4*)(beta + fl * 8);
  float4 b1 = *(const float4*)(beta + fl * 8 + 4);
  float gg[8] = {g0.x, g0.y, g0.z, g0.w, g1.x, g1.y, g1.z, g1.w};
  float bb[8] = {b0.x, b0.y, b0.z, b0.w, b1.x, b1.y, b1.z, b1.w};
#pragma unroll
  for (int k = 0; k < 8; ++k) o[k] = fmaxf((h[k] - mu) * scale * gg[k] + bb[k], 0.f);
}

__device__ __forceinline__ uint4 pack8(const float* v) {
  uint4 u;
  u.x = pk2(v[0], v[1]); u.y = pk2(v[2], v[3]);
  u.z = pk2(v[4], v[5]); u.w = pk2(v[6], v[7]);
  return u;
}

__device__ __forceinline__ void body_agg1(const Params& p, int w, int lane) {
  int fl = lane & 15;
  float a[8] = {0.f, 0.f, 0.f, 0.f, 0.f, 0.f, 0.f, 0.f};
  gather_mean(p.Abf, p.rowptr, p.srclist, w, lane, a);
  uint4 qv = ((const uint4*)p.Qbf)[(size_t)w * 16 + fl];
  float4 bl0 = *(const float4*)(p.b_l + fl * 8);
  float4 bl1 = *(const float4*)(p.b_l + fl * 8 + 4);
  float q[8] = {bflo(qv.x), bfhi(qv.x), bflo(qv.y), bfhi(qv.y), bflo(qv.z), bfhi(qv.z), bflo(qv.w), bfhi(qv.w)};
  float bl[8] = {bl0.x, bl0.y, bl0.z, bl0.w, bl1.x, bl1.y, bl1.z, bl1.w};
  float h[8];
#pragma unroll
  for (int k = 0; k < 8; ++k) h[k] = a[k] + q[k] + bl[k];
  float r[8];
  ln_relu8(h, p.gamma, p.beta, fl, r);
  if (lane < 16) {
    ((uint4*)p.H1)[(size_t)w * 16 + fl] = pack8(h);
    ((uint4*)p.Dbf)[(size_t)w * 16 + fl] = pack8(r);
  }
}

__device__ __forceinline__ void body_agg2(const Params& p, int w, int lane) {
  int fl = lane & 15;
  float a[8] = {0.f, 0.f, 0.f, 0.f, 0.f, 0.f, 0.f, 0.f};
  gather_mean(p.Abf, p.rowptr, p.srclist, w, lane, a);
  uint4 vv = ((const uint4*)p.Qbf)[(size_t)w * 16 + fl];
  uint4 hv = ((const uint4*)p.H1)[(size_t)w * 16 + fl];
  float4 bl0 = *(const float4*)(p.b_l + fl * 8);
  float4 bl1 = *(const float4*)(p.b_l + fl * 8 + 4);
  float vf[8] = {bflo(vv.x), bfhi(vv.x), bflo(vv.y), bfhi(vv.y), bflo(vv.z), bfhi(vv.z), bflo(vv.w), bfhi(vv.w)};
  float hf[8] = {bflo(hv.x), bfhi(hv.x), bflo(hv.y), bfhi(hv.y), bflo(hv.z), bfhi(hv.z), bflo(hv.w), bfhi(hv.w)};
  float bl[8] = {bl0.x, bl0.y, bl0.z, bl0.w, bl1.x, bl1.y, bl1.z, bl1.w};
  float h[8];
#pragma unroll
  for (int k = 0; k < 8; ++k) h[k] = a[k] + vf[k] + bl[k] + hf[k];
  float o[8];
  ln_relu8(h, p.gamma, p.beta, fl, o);
  if (lane < 16) ((uint4*)p.Dbf)[(size_t)w * 16 + fl] = pack8(o);
}

// ================= fused cooperative kernel =================

__global__ __launch_bounds__(256, 4) void k_fused(Params p) {
  cg::grid_group grid = cg::this_grid();
  const int tid = threadIdx.x, bid = blockIdx.x, G = gridDim.x;
  const int gt = bid * 256 + tid, nt = G * 256;
  __shared__ int sh[256];

  // P0: zero cnt + cast x -> bf16
  body_zero_cast(p, gt, nt);
  __threadfence(); grid.sync();

  // P1: histogram
  body_hist(p, gt, nt);
  __threadfence(); grid.sync();

  // P2: scan1 | weight prep (WA,WB,bA,bB) | weight casts
  if (bid < p.nbS) body_scan1(p, bid, tid, sh);
  else if (bid < p.nbS + 129) body_prep(p, bid - p.nbS, tid, (float*)sh);
  else body_wcast(p, bid - (p.nbS + 129), G - (p.nbS + 129), tid);
  __threadfence(); grid.sync();

  // P3: scan2 (block 0) | GEMM1 jobs part A
  const int J3 = min(2 * p.nbT, G - 1);
  if (bid == 0) body_scan2(p, tid, sh);
  else if (bid - 1 < J3) gemm_job1(p, bid - 1);
  __threadfence(); grid.sync();

  // P4: rowptr/cursor | GEMM1 jobs part B
  if (bid < p.nbS) body_rowptr(p, bid, tid);
  else
    for (int job = J3 + (bid - p.nbS); job < 2 * p.nbT; job += (G - p.nbS)) gemm_job1(p, job);
  __threadfence(); grid.sync();

  // P5: CSR fill
  body_fill(p, gt, nt);
  __threadfence(); grid.sync();

  // P6: agg1 (mean + h1 + LN + ReLU)
  {
    int lane = tid & 63, gw = gt >> 6, nw = nt >> 6;
    for (int w = gw; w < p.N; w += nw) body_agg1(p, w, lane);
  }
  __threadfence(); grid.sync();

  // P7: GEMM2 pair (U = r@W_l, V = r@W_r)
  for (int job = bid; job < 2 * p.nbT; job += G) gemm_job2(p, job);
  __threadfence(); grid.sync();

  // P8: agg2
  {
    int lane = tid & 63, gw = gt >> 6, nw = nt >> 6;
    for (int w = gw; w < p.N; w += nw) body_agg2(p, w, lane);
  }
  __threadfence(); grid.sync();

  // P9: out = o@W_lin + b_lin
  for (int job = bid; job < p.nbT; job += G) gemm_jobO(p, job);
}

// ================= fallback kernels (normal launches) =================

__global__ __launch_bounds__(256) void k_p0(Params p) {
  body_zero_cast(p, blockIdx.x * 256 + threadIdx.x, gridDim.x * 256);
}
__global__ __launch_bounds__(256) void k_hist_k(Params p) {
  body_hist(p, blockIdx.x * 256 + threadIdx.x, gridDim.x * 256);
}
__global__ __launch_bounds__(256) void k_p2(Params p) {
  __shared__ int sh[256];
  int bid = blockIdx.x;
  if (bid < p.nbS) body_scan1(p, bid, threadIdx.x, sh);
  else if (bid < p.nbS + 129) body_prep(p, bid - p.nbS, threadIdx.x, (float*)sh);
  else body_wcast(p, bid - (p.nbS + 129), gridDim.x - (p.nbS + 129), threadIdx.x);
}
__global__ __launch_bounds__(256) void k_scan2_k(Params p) {
  __shared__ int sh[256];
  body_scan2(p, threadIdx.x, sh);
}
__global__ __launch_bounds__(256) void k_p4(Params p) {
  int bid = blockIdx.x;
  if (bid < p.nbS) body_rowptr(p, bid, threadIdx.x);
  else gemm_job1(p, bid - p.nbS);
}
__global__ __launch_bounds__(256) void k_fill_k(Params p) {
  body_fill(p, blockIdx.x * 256 + threadIdx.x, gridDim.x * 256);
}
__global__ __launch_bounds__(256) void k_agg1_k(Params p) {
  int w = (blockIdx.x * 256 + threadIdx.x) >> 6;
  if (w < p.N) body_agg1(p, w, threadIdx.x & 63);
}
__global__ __launch_bounds__(256) void k_gemm2_k(Params p) {
  gemm_job2(p, blockIdx.y * p.nbT + blockIdx.x);
}
__global__ __launch_bounds__(256) void k_agg2_k(Params p) {
  int w = (blockIdx.x * 256 + threadIdx.x) >> 6;
  if (w < p.N) body_agg2(p, w, threadIdx.x & 63);
}
__global__ __launch_bounds__(256) void k_gout_k(Params p) {
  gemm_jobO(p, blockIdx.x);
}

// ================= launch =================

extern "C" void kernel_launch(void* const* d_in, const int* in_sizes, int n_in,
                              void* d_out, int out_size, void* d_ws, size_t ws_size,
                              hipStream_t stream) {
  Params p;
  p.x = (const float*)d_in[0];
  p.ei = (const int*)d_in[1];
  // d_in[2] = edge_attr: unused by the reference
  p.W_ne = (const float*)d_in[3];
  p.b_ne = (const float*)d_in[4];
  p.W_l = (const float*)d_in[5];
  p.b_l = (const float*)d_in[6];
  p.W_r = (const float*)d_in[7];
  p.gamma = (const float*)d_in[8];
  p.beta = (const float*)d_in[9];
  p.W_lin = (const float*)d_in[10];
  p.b_lin = (const float*)d_in[11];
  p.out = (float*)d_out;

  p.N = in_sizes[0] / 128;
  p.E = in_sizes[1] / 2;
  p.nbS = (p.N + 255) / 256;
  p.nbT = (p.N + 63) / 64;

  char* w = (char*)d_ws;
  const size_t S2 = (size_t)p.N * 128 * sizeof(ushort);
  p.Abf = (ushort*)w;    w += S2;
  p.Qbf = (ushort*)w;    w += S2;
  p.H1 = (ushort*)w;     w += S2;
  p.Dbf = (ushort*)w;    w += S2;
  p.xbf = (ushort*)w;    w += S2;
  p.WAt = (ushort*)w;    w += 128 * 128 * sizeof(ushort);
  p.WBt = (ushort*)w;    w += 128 * 128 * sizeof(ushort);
  p.Wlt = (ushort*)w;    w += 128 * 128 * sizeof(ushort);
  p.Wrt = (ushort*)w;    w += 128 * 128 * sizeof(ushort);
  p.Wlint = (ushort*)w;  w += 64 * 128 * sizeof(ushort);
  p.bA = (float*)w;      w += 128 * sizeof(float);
  p.bB = (float*)w;      w += 128 * sizeof(float);
  p.cnt = (int*)w;       w += (size_t)p.N * sizeof(int);
  p.incl = (int*)w;      w += (size_t)p.N * sizeof(int);
  p.rowptr = (int*)w;    w += ((size_t)p.N + 4) * sizeof(int);
  p.cursor = (int*)w;    w += (size_t)p.N * sizeof(int);
  p.bsums = (int*)w;     w += 1024 * sizeof(int);
  p.srclist = (int*)w;

  // ---- try cooperative fused launch, sized by what the runtime says fits ----
  hipError_t le = hipErrorUnknown;
  int dev = 0;
  hipGetDevice(&dev);
  int cuCount = 0, coop = 0, maxB = 0;
  hipDeviceGetAttribute(&cuCount, hipDeviceAttributeMultiprocessorCount, dev);
  hipDeviceGetAttribute(&coop, hipDeviceAttributeCooperativeLaunch, dev);
  hipError_t oe = hipOccupancyMaxActiveBlocksPerMultiprocessor(&maxB, (const void*)k_fused, 256, 0);
  if (coop && oe == hipSuccess && cuCount > 0 && maxB > 0) {
    long long g = (long long)cuCount * maxB;
    if (g > 2048) g = 2048;
    if (g >= 512) {
      Params pl = p;
      void* args[] = {&pl};
      le = hipLaunchCooperativeKernel((const void*)k_fused, dim3((uint)g), dim3(256), args, 0, stream);
    }
  }

  if (le != hipSuccess) {
    // ---- fallback: same bodies, 10 normal dispatches ----
    const int nbE = (p.E + 255) / 256;
    const int nbW = ((p.N * 64) + 255) / 256;
    k_p0<<<2048, 256, 0, stream>>>(p);
    k_hist_k<<<nbE, 256, 0, stream>>>(p);
    k_p2<<<p.nbS + 129 + 160, 256, 0, stream>>>(p);
    k_scan2_k<<<1, 256, 0, stream>>>(p);
    k_p4<<<p.nbS + 2 * p.nbT, 256, 0, stream>>>(p);
    k_fill_k<<<nbE, 256, 0, stream>>>(p);
    k_agg1_k<<<nbW, 256, 0, stream>>>(p);
    k_gemm2_k<<<dim3(p.nbT, 2), 256, 0, stream>>>(p);
    k_agg2_k<<<nbW, 256, 0, stream>>>(p);
    k_gout_k<<<p.nbT, 256, 0, stream>>>(p);
  }
}

// Round 7
// 300.671 us; speedup vs baseline: 4.4026x; 4.4026x over previous
//
#include <hip/hip_runtime.h>

typedef __attribute__((ext_vector_type(8))) short bf16x8;
typedef __attribute__((ext_vector_type(4))) float f32x4;

constexpr float LN_EPS = 1e-5f;

__device__ inline ushort f2bf(float f) {
  uint u = __float_as_uint(f);
  u += 0x7FFF + ((u >> 16) & 1);   // round-to-nearest-even
  return (ushort)(u >> 16);
}
__device__ inline float bflo(uint u) { return __uint_as_float(u << 16); }
__device__ inline float bfhi(uint u) { return __uint_as_float(u & 0xFFFF0000u); }
__device__ inline uint pk2(float lo, float hi) { return (uint)f2bf(lo) | ((uint)f2bf(hi) << 16); }

struct Params {
  const float* x; const int* ei;
  const float *W_ne, *b_ne, *W_l, *b_l, *W_r, *gamma, *beta, *W_lin, *b_lin;
  float* out;
  ushort *Abf, *Qbf, *H1, *Dbf, *WAt, *WBt, *Wlt, *Wrt, *Wlint;
  float *bA, *bB;
  int *cnt, *incl, *rowptr, *cursor, *bsums, *srclist;
  int N, E, nbS, nbT;
};

// ================= CSR bodies =================

__global__ __launch_bounds__(256) void k_hist(Params p) {
  int e = blockIdx.x * 256 + threadIdx.x;
  if (e < p.E) atomicAdd(&p.cnt[p.ei[p.E + e]], 1);
}

// scan1 (blocks < nbS) | WA/WB/bias prep (129 blocks) | W_l/W_r/W_lin transpose-casts (rest)
__global__ __launch_bounds__(256) void k_p2(Params p) {
  __shared__ int sh[256];
  const int tid = threadIdx.x, bid = blockIdx.x;
  if (bid < p.nbS) {
    int i = bid * 256 + tid;
    int v = (i < p.N) ? p.cnt[i] : 0;
    sh[tid] = v;
    __syncthreads();
    for (int off = 1; off < 256; off <<= 1) {
      int t = (tid >= off) ? sh[tid - off] : 0;
      __syncthreads();
      sh[tid] += t;
      __syncthreads();
    }
    if (i < p.N) p.incl[i] = sh[tid];
    if (tid == 255) p.bsums[bid] = sh[255];
  } else if (bid < p.nbS + 129) {
    int blk = bid - p.nbS;
    float* srow = (float*)sh;
    const float* src = (blk < 128) ? (p.W_ne + blk * 128) : p.b_ne;
    if (tid < 128) srow[tid] = src[tid];
    __syncthreads();
    int col = tid & 127;
    const float* Wx = (tid < 128) ? p.W_l : p.W_r;
    float acc = 0.f;
#pragma unroll 8
    for (int k = 0; k < 128; ++k) acc = fmaf(srow[k], Wx[k * 128 + col], acc);
    if (blk < 128) {
      ushort* dst = (tid < 128) ? p.WAt : p.WBt;
      dst[col * 128 + blk] = f2bf(acc);
    } else {
      float* dst = (tid < 128) ? p.bA : p.bB;
      dst[col] = acc;
    }
  } else {
    int i0 = (bid - (p.nbS + 129)) * 256 + tid, st = (gridDim.x - (p.nbS + 129)) * 256;
    for (int t = i0; t < 16384; t += st) p.Wlt[(t & 127) * 128 + (t >> 7)] = f2bf(p.W_l[t]);
    for (int t = i0; t < 16384; t += st) p.Wrt[(t & 127) * 128 + (t >> 7)] = f2bf(p.W_r[t]);
    for (int t = i0; t < 8192; t += st) p.Wlint[(t & 63) * 128 + (t >> 6)] = f2bf(p.W_lin[t]);
  }
}

__global__ __launch_bounds__(256) void k_scan2(Params p) {
  __shared__ int sh[256];
  const int tid = threadIdx.x;
  int v = (tid < p.nbS) ? p.bsums[tid] : 0;
  sh[tid] = v;
  __syncthreads();
  for (int off = 1; off < 256; off <<= 1) {
    int t = (tid >= off) ? sh[tid - off] : 0;
    __syncthreads();
    sh[tid] += t;
    __syncthreads();
  }
  if (tid < p.nbS) p.bsums[tid] = sh[tid] - v;  // exclusive
}

__global__ __launch_bounds__(256) void k_fill(Params p) {
  int e = blockIdx.x * 256 + threadIdx.x;
  if (e >= p.E) return;
  int s = p.ei[e], d = p.ei[p.E + e];
  int pos = atomicAdd(&p.cursor[d], 1);
  p.srclist[pos] = s;
}

// ================= no-LDS MFMA GEMM tile =================
// 64 rows x NCOL cols, 4 waves (2x2). A from global (fp32 converted in-reg, or bf16).
// Wt bf16 [NCOL][128] transposed.

template <int NCOL, bool BF16OUT, bool F32A>
__device__ __forceinline__ void gemm_tile(const void* __restrict__ Xv, const ushort* __restrict__ Wt,
                                          const float* __restrict__ bias, void* __restrict__ Yv,
                                          int M, int tile) {
  constexpr int NF = NCOL / 32;
  const int tid = threadIdx.x;
  const int wave = tid >> 6, lane = tid & 63;
  const int rbase = (wave >> 1) * 32;
  const int cbase = (wave & 1) * (NCOL / 2);
  const int lrow = lane & 15, lkb = (lane >> 4) * 8;
  const int row0 = tile * 64;

  size_t rIdx[2];
#pragma unroll
  for (int mf = 0; mf < 2; ++mf) {
    int r = row0 + rbase + mf * 16 + lrow;
    rIdx[mf] = (size_t)((r < M) ? r : (M - 1));
  }

  f32x4 acc[2][NF];
#pragma unroll
  for (int mf = 0; mf < 2; ++mf)
#pragma unroll
    for (int nf = 0; nf < NF; ++nf) acc[mf][nf] = (f32x4){0.f, 0.f, 0.f, 0.f};

#pragma unroll
  for (int ks = 0; ks < 4; ++ks) {
    bf16x8 a[2], b[NF];
#pragma unroll
    for (int mf = 0; mf < 2; ++mf) {
      if constexpr (F32A) {
        const float* Xf = (const float*)Xv + rIdx[mf] * 128 + ks * 32 + lkb;
        float4 lo = *(const float4*)Xf;
        float4 hi = *(const float4*)(Xf + 4);
        uint4 v;
        v.x = pk2(lo.x, lo.y); v.y = pk2(lo.z, lo.w);
        v.z = pk2(hi.x, hi.y); v.w = pk2(hi.z, hi.w);
        a[mf] = *reinterpret_cast<bf16x8*>(&v);
      } else {
        a[mf] = *(const bf16x8*)((const ushort*)Xv + rIdx[mf] * 128 + ks * 32 + lkb);
      }
    }
#pragma unroll
    for (int nf = 0; nf < NF; ++nf)
      b[nf] = *(const bf16x8*)(Wt + (size_t)(cbase + nf * 16 + lrow) * 128 + ks * 32 + lkb);
#pragma unroll
    for (int mf = 0; mf < 2; ++mf)
#pragma unroll
      for (int nf = 0; nf < NF; ++nf)
        acc[mf][nf] = __builtin_amdgcn_mfma_f32_16x16x32_bf16(a[mf], b[nf], acc[mf][nf], 0, 0, 0);
  }

#pragma unroll
  for (int nf = 0; nf < NF; ++nf) {
    int col = cbase + nf * 16 + lrow;
    float bv = bias ? bias[col] : 0.f;
#pragma unroll
    for (int mf = 0; mf < 2; ++mf) {
      int growb = row0 + rbase + mf * 16 + (lane >> 4) * 4;
#pragma unroll
      for (int r = 0; r < 4; ++r) {
        int grow = growb + r;
        if (grow < M) {
          float val = acc[mf][nf][r] + bv;
          if constexpr (BF16OUT)
            ((ushort*)Yv)[(size_t)grow * NCOL + col] = f2bf(val);
          else
            ((float*)Yv)[(size_t)grow * NCOL + col] = val;
        }
      }
    }
  }
}

// rowptr/cursor (blocks < nbS) | GEMM1 pair: Pp = x@WA+bA, Pq = x@WB+bB (fp32 A, in-reg cast)
__global__ __launch_bounds__(256) void k_p4(Params p) {
  const int bid = blockIdx.x, tid = threadIdx.x;
  if (bid < p.nbS) {
    int i = bid * 256 + tid;
    if (i < p.N) {
      int inc = p.incl[i] + p.bsums[bid];
      p.rowptr[i + 1] = inc;
      p.cursor[i] = inc - p.cnt[i];
    }
    if (i == 0) p.rowptr[0] = 0;
    return;
  }
  int job = bid - p.nbS;
  if (job < p.nbT) gemm_tile<128, true, true>(p.x, p.WAt, p.bA, p.Abf, p.N, job);
  else gemm_tile<128, true, true>(p.x, p.WBt, p.bB, p.Qbf, p.N, job - p.nbT);
}

__global__ __launch_bounds__(256) void k_gemm2(Params p) {
  int job = blockIdx.y * p.nbT + blockIdx.x;
  if (job < p.nbT) gemm_tile<128, true, false>(p.Dbf, p.Wlt, nullptr, p.Abf, p.N, job);
  else gemm_tile<128, true, false>(p.Dbf, p.Wrt, nullptr, p.Qbf, p.N, job - p.nbT);
}

__global__ __launch_bounds__(256) void k_gout(Params p) {
  gemm_tile<64, false, false>(p.Dbf, p.Wlint, p.b_lin, p.out, p.N, blockIdx.x);
}

// ================= gather/LN (wave per node, 8 edges in flight) =================

__device__ __forceinline__ void acc8(uint4 u, float* a) {
  a[0] += bflo(u.x); a[1] += bfhi(u.x);
  a[2] += bflo(u.y); a[3] += bfhi(u.y);
  a[4] += bflo(u.z); a[5] += bfhi(u.z);
  a[6] += bflo(u.w); a[7] += bfhi(u.w);
}

__device__ __forceinline__ void gather_mean(const ushort* __restrict__ Pm, const int* __restrict__ rowptr,
                                            const int* __restrict__ srclist, int w, int lane, float* a) {
  const uint4* Pv = (const uint4*)Pm;
  int fl = lane & 15, g4 = lane >> 4;
  int beg = rowptr[w], end = rowptr[w + 1];
  for (int base = beg; base < end; base += 64) {
    int m = end - base;
    if (m > 64) m = 64;
    int sidx = (lane < m) ? srclist[base + lane] : 0;
    for (int i = 0; i < m; i += 8) {
      int j0 = i + g4, j1 = j0 + 4;
      int s0 = __shfl(sidx, j0 & 63, 64);
      int s1 = __shfl(sidx, j1 & 63, 64);
      uint4 z = make_uint4(0u, 0u, 0u, 0u);
      uint4 u0 = (j0 < m) ? Pv[(size_t)s0 * 16 + fl] : z;
      uint4 u1 = (j1 < m) ? Pv[(size_t)s1 * 16 + fl] : z;
      acc8(u0, a);
      acc8(u1, a);
    }
  }
#pragma unroll
  for (int k = 0; k < 8; ++k) {
    a[k] += __shfl_xor(a[k], 16, 64);
    a[k] += __shfl_xor(a[k], 32, 64);
  }
  float inv = 1.f / fmaxf((float)(end - beg), 1.f);
#pragma unroll
  for (int k = 0; k < 8; ++k) a[k] *= inv;
}

__device__ __forceinline__ void ln_relu8(const float* h, const float* __restrict__ gamma,
                                         const float* __restrict__ beta, int fl, float* o) {
  float sum = 0.f;
#pragma unroll
  for (int k = 0; k < 8; ++k) sum += h[k];
#pragma unroll
  for (int off = 1; off < 16; off <<= 1) sum += __shfl_xor(sum, off, 64);
  float mu = sum * (1.f / 128.f);
  float s2 = 0.f;
#pragma unroll
  for (int k = 0; k < 8; ++k) { float d = h[k] - mu; s2 += d * d; }
#pragma unroll
  for (int off = 1; off < 16; off <<= 1) s2 += __shfl_xor(s2, off, 64);
  float scale = rsqrtf(s2 * (1.f / 128.f) + LN_EPS);
  float4 g0 = *(const float4*)(gamma + fl * 8);
  float4 g1 = *(const float4*)(gamma + fl * 8 + 4);
  float4 b0 = *(const float4*)(beta + fl * 8);
  float4 b1 = *(const float4*)(beta + fl * 8 + 4);
  float gg[8] = {g0.x, g0.y, g0.z, g0.w, g1.x, g1.y, g1.z, g1.w};
  float bb[8] = {b0.x, b0.y, b0.z, b0.w, b1.x, b1.y, b1.z, b1.w};
#pragma unroll
  for (int k = 0; k < 8; ++k) o[k] = fmaxf((h[k] - mu) * scale * gg[k] + bb[k], 0.f);
}

__device__ __forceinline__ uint4 pack8(const float* v) {
  uint4 u;
  u.x = pk2(v[0], v[1]); u.y = pk2(v[2], v[3]);
  u.z = pk2(v[4], v[5]); u.w = pk2(v[6], v[7]);
  return u;
}

// agg1: h1 = mean(Pp)+Pq+b_l -> H1 (bf16); r = relu(LN(h1)) -> Dbf (bf16)
__global__ __launch_bounds__(256) void k_agg1(Params p) {
  int w = (blockIdx.x * 256 + threadIdx.x) >> 6;
  int lane = threadIdx.x & 63;
  if (w >= p.N) return;
  int fl = lane & 15;
  float a[8] = {0.f, 0.f, 0.f, 0.f, 0.f, 0.f, 0.f, 0.f};
  gather_mean(p.Abf, p.rowptr, p.srclist, w, lane, a);
  uint4 qv = ((const uint4*)p.Qbf)[(size_t)w * 16 + fl];
  float4 bl0 = *(const float4*)(p.b_l + fl * 8);
  float4 bl1 = *(const float4*)(p.b_l + fl * 8 + 4);
  float q[8] = {bflo(qv.x), bfhi(qv.x), bflo(qv.y), bfhi(qv.y), bflo(qv.z), bfhi(qv.z), bflo(qv.w), bfhi(qv.w)};
  float bl[8] = {bl0.x, bl0.y, bl0.z, bl0.w, bl1.x, bl1.y, bl1.z, bl1.w};
  float h[8];
#pragma unroll
  for (int k = 0; k < 8; ++k) h[k] = a[k] + q[k] + bl[k];
  float r[8];
  ln_relu8(h, p.gamma, p.beta, fl, r);
  if (lane < 16) {
    ((uint4*)p.H1)[(size_t)w * 16 + fl] = pack8(h);
    ((uint4*)p.Dbf)[(size_t)w * 16 + fl] = pack8(r);
  }
}

// agg2: o = relu(LN(mean(U)+V+b_l+h1)) -> Dbf (bf16)
__global__ __launch_bounds__(256) void k_agg2(Params p) {
  int w = (blockIdx.x * 256 + threadIdx.x) >> 6;
  int lane = threadIdx.x & 63;
  if (w >= p.N) return;
  int fl = lane & 15;
  float a[8] = {0.f, 0.f, 0.f, 0.f, 0.f, 0.f, 0.f, 0.f};
  gather_mean(p.Abf, p.rowptr, p.srclist, w, lane, a);
  uint4 vv = ((const uint4*)p.Qbf)[(size_t)w * 16 + fl];
  uint4 hv = ((const uint4*)p.H1)[(size_t)w * 16 + fl];
  float4 bl0 = *(const float4*)(p.b_l + fl * 8);
  float4 bl1 = *(const float4*)(p.b_l + fl * 8 + 4);
  float vf[8] = {bflo(vv.x), bfhi(vv.x), bflo(vv.y), bfhi(vv.y), bflo(vv.z), bfhi(vv.z), bflo(vv.w), bfhi(vv.w)};
  float hf[8] = {bflo(hv.x), bfhi(hv.x), bflo(hv.y), bfhi(hv.y), bflo(hv.z), bfhi(hv.z), bflo(hv.w), bfhi(hv.w)};
  float bl[8] = {bl0.x, bl0.y, bl0.z, bl0.w, bl1.x, bl1.y, bl1.z, bl1.w};
  float h[8];
#pragma unroll
  for (int k = 0; k < 8; ++k) h[k] = a[k] + vf[k] + bl[k] + hf[k];
  float o[8];
  ln_relu8(h, p.gamma, p.beta, fl, o);
  if (lane < 16) ((uint4*)p.Dbf)[(size_t)w * 16 + fl] = pack8(o);
}

// ================= launch =================

extern "C" void kernel_launch(void* const* d_in, const int* in_sizes, int n_in,
                              void* d_out, int out_size, void* d_ws, size_t ws_size,
                              hipStream_t stream) {
  Params p;
  p.x = (const float*)d_in[0];
  p.ei = (const int*)d_in[1];
  // d_in[2] = edge_attr: unused by the reference
  p.W_ne = (const float*)d_in[3];
  p.b_ne = (const float*)d_in[4];
  p.W_l = (const float*)d_in[5];
  p.b_l = (const float*)d_in[6];
  p.W_r = (const float*)d_in[7];
  p.gamma = (const float*)d_in[8];
  p.beta = (const float*)d_in[9];
  p.W_lin = (const float*)d_in[10];
  p.b_lin = (const float*)d_in[11];
  p.out = (float*)d_out;

  p.N = in_sizes[0] / 128;
  p.E = in_sizes[1] / 2;
  p.nbS = (p.N + 255) / 256;
  p.nbT = (p.N + 63) / 64;

  char* w = (char*)d_ws;
  const size_t S2 = (size_t)p.N * 128 * sizeof(ushort);
  p.Abf = (ushort*)w;    w += S2;
  p.Qbf = (ushort*)w;    w += S2;
  p.H1 = (ushort*)w;     w += S2;
  p.Dbf = (ushort*)w;    w += S2;
  p.WAt = (ushort*)w;    w += 128 * 128 * sizeof(ushort);
  p.WBt = (ushort*)w;    w += 128 * 128 * sizeof(ushort);
  p.Wlt = (ushort*)w;    w += 128 * 128 * sizeof(ushort);
  p.Wrt = (ushort*)w;    w += 128 * 128 * sizeof(ushort);
  p.Wlint = (ushort*)w;  w += 64 * 128 * sizeof(ushort);
  p.bA = (float*)w;      w += 128 * sizeof(float);
  p.bB = (float*)w;      w += 128 * sizeof(float);
  p.cnt = (int*)w;       w += (size_t)p.N * sizeof(int);
  p.incl = (int*)w;      w += (size_t)p.N * sizeof(int);
  p.rowptr = (int*)w;    w += ((size_t)p.N + 4) * sizeof(int);
  p.cursor = (int*)w;    w += (size_t)p.N * sizeof(int);
  p.bsums = (int*)w;     w += 1024 * sizeof(int);
  p.srclist = (int*)w;

  const int nbE = (p.E + 255) / 256;
  const int nbW = ((p.N * 64) + 255) / 256;

  hipMemsetAsync(p.cnt, 0, (size_t)p.N * sizeof(int), stream);
  k_hist<<<nbE, 256, 0, stream>>>(p);
  k_p2<<<p.nbS + 129 + 256, 256, 0, stream>>>(p);
  k_scan2<<<1, 256, 0, stream>>>(p);
  k_p4<<<p.nbS + 2 * p.nbT, 256, 0, stream>>>(p);
  k_fill<<<nbE, 256, 0, stream>>>(p);
  k_agg1<<<nbW, 256, 0, stream>>>(p);
  k_gemm2<<<dim3(p.nbT, 2), 256, 0, stream>>>(p);
  k_agg2<<<nbW, 256, 0, stream>>>(p);
  k_gout<<<p.nbT, 256, 0, stream>>>(p);
}

// Round 8
// 251.347 us; speedup vs baseline: 5.2666x; 1.1962x over previous
//
#include <hip/hip_runtime.h>

typedef __attribute__((ext_vector_type(8))) short bf16x8;
typedef __attribute__((ext_vector_type(4))) float f32x4;

constexpr float LN_EPS = 1e-5f;

__device__ inline ushort f2bf(float f) {
  uint u = __float_as_uint(f);
  u += 0x7FFF + ((u >> 16) & 1);   // round-to-nearest-even
  return (ushort)(u >> 16);
}
__device__ inline float bflo(uint u) { return __uint_as_float(u << 16); }
__device__ inline float bfhi(uint u) { return __uint_as_float(u & 0xFFFF0000u); }
__device__ inline uint pk2(float lo, float hi) { return (uint)f2bf(lo) | ((uint)f2bf(hi) << 16); }

struct Params {
  const float* x; const int* ei;
  const float *W_ne, *b_ne, *W_l, *b_l, *W_r, *gamma, *beta, *W_lin, *b_lin;
  float* out;
  ushort *Abf, *Qbf, *H1, *Dbf, *xbf, *WAt, *WBt, *Wlt, *Wrt, *Wlint;
  float *bA, *bB;
  int *cnt, *incl, *rowptr, *cursor, *bsums, *srclist;
  int N, E, nbS, nbT;
};

// ================= CSR + prep =================

__global__ __launch_bounds__(256) void k_hist(Params p) {
  int e = blockIdx.x * 256 + threadIdx.x;
  if (e < p.E) atomicAdd(&p.cnt[p.ei[p.E + e]], 1);
}

// scan1 (nbS blocks) | WA/WB/bias prep (129 blocks) | x-cast + weight transpose-casts (rest, grid-stride)
__global__ __launch_bounds__(256) void k_p2(Params p) {
  __shared__ int sh[256];
  const int tid = threadIdx.x, bid = blockIdx.x;
  if (bid < p.nbS) {
    int i = bid * 256 + tid;
    int v = (i < p.N) ? p.cnt[i] : 0;
    sh[tid] = v;
    __syncthreads();
    for (int off = 1; off < 256; off <<= 1) {
      int t = (tid >= off) ? sh[tid - off] : 0;
      __syncthreads();
      sh[tid] += t;
      __syncthreads();
    }
    if (i < p.N) p.incl[i] = sh[tid];
    if (tid == 255) p.bsums[bid] = sh[255];
  } else if (bid < p.nbS + 129) {
    int blk = bid - p.nbS;
    float* srow = (float*)sh;
    const float* src = (blk < 128) ? (p.W_ne + blk * 128) : p.b_ne;
    if (tid < 128) srow[tid] = src[tid];
    __syncthreads();
    int col = tid & 127;
    const float* Wx = (tid < 128) ? p.W_l : p.W_r;
    float acc = 0.f;
#pragma unroll 8
    for (int k = 0; k < 128; ++k) acc = fmaf(srow[k], Wx[k * 128 + col], acc);
    if (blk < 128) {
      ushort* dst = (tid < 128) ? p.WAt : p.WBt;
      dst[col * 128 + blk] = f2bf(acc);
    } else {
      float* dst = (tid < 128) ? p.bA : p.bB;
      dst[col] = acc;
    }
  } else {
    const int nx16 = p.N * 16;
    const int total = nx16 + 16384 + 16384 + 8192;
    const int i0 = (bid - (p.nbS + 129)) * 256 + tid;
    const int st = (gridDim.x - (p.nbS + 129)) * 256;
    const float4* xin = (const float4*)p.x;
    uint4* xo = (uint4*)p.xbf;
    for (int idx = i0; idx < total; idx += st) {
      if (idx < nx16) {
        float4 a = xin[2 * (size_t)idx], b = xin[2 * (size_t)idx + 1];
        uint4 v;
        v.x = pk2(a.x, a.y); v.y = pk2(a.z, a.w);
        v.z = pk2(b.x, b.y); v.w = pk2(b.z, b.w);
        xo[idx] = v;
        continue;
      }
      int t = idx - nx16;
      if (t < 16384) { p.Wlt[(t & 127) * 128 + (t >> 7)] = f2bf(p.W_l[t]); continue; }
      t -= 16384;
      if (t < 16384) { p.Wrt[(t & 127) * 128 + (t >> 7)] = f2bf(p.W_r[t]); continue; }
      t -= 16384;
      p.Wlint[(t & 63) * 128 + (t >> 6)] = f2bf(p.W_lin[t]);
    }
  }
}

__global__ __launch_bounds__(256) void k_scan2(Params p) {
  __shared__ int sh[256];
  const int tid = threadIdx.x;
  int v = (tid < p.nbS) ? p.bsums[tid] : 0;
  sh[tid] = v;
  __syncthreads();
  for (int off = 1; off < 256; off <<= 1) {
    int t = (tid >= off) ? sh[tid - off] : 0;
    __syncthreads();
    sh[tid] += t;
    __syncthreads();
  }
  if (tid < p.nbS) p.bsums[tid] = sh[tid] - v;  // exclusive
}

__global__ __launch_bounds__(256) void k_fill(Params p) {
  int e = blockIdx.x * 256 + threadIdx.x;
  if (e >= p.E) return;
  int s = p.ei[e], d = p.ei[p.E + e];
  int pos = atomicAdd(&p.cursor[d], 1);
  p.srclist[pos] = s;
}

// ================= no-LDS MFMA GEMM (R4 body): 128 rows x NCOL, 4 waves 2x2 =================
// X bf16 [M][128]; Wt bf16 [NCOL][128] transposed.

template <int NCOL, bool BF16OUT>
__device__ __forceinline__ void gemm_tile(const ushort* __restrict__ X, const ushort* __restrict__ Wt,
                                          const float* __restrict__ bias, void* __restrict__ Yv,
                                          int M, int tile) {
  constexpr int NF = NCOL / 32;
  const int tid = threadIdx.x;
  const int wave = tid >> 6, lane = tid & 63;
  const int rbase = (wave >> 1) * 64;
  const int cbase = (wave & 1) * (NCOL / 2);
  const int lrow = lane & 15;
  const int lkb = (lane >> 4) * 8;
  const int row0 = tile * 128;

  size_t rIdx[4];
#pragma unroll
  for (int mf = 0; mf < 4; ++mf) {
    int r = row0 + rbase + mf * 16 + lrow;
    rIdx[mf] = (size_t)((r < M) ? r : (M - 1));
  }

  f32x4 acc[4][NF];
#pragma unroll
  for (int mf = 0; mf < 4; ++mf)
#pragma unroll
    for (int nf = 0; nf < NF; ++nf) acc[mf][nf] = (f32x4){0.f, 0.f, 0.f, 0.f};

#pragma unroll
  for (int ks = 0; ks < 4; ++ks) {
    bf16x8 a[4], b[NF];
#pragma unroll
    for (int mf = 0; mf < 4; ++mf)
      a[mf] = *(const bf16x8*)(X + rIdx[mf] * 128 + ks * 32 + lkb);
#pragma unroll
    for (int nf = 0; nf < NF; ++nf)
      b[nf] = *(const bf16x8*)(Wt + (size_t)(cbase + nf * 16 + lrow) * 128 + ks * 32 + lkb);
#pragma unroll
    for (int mf = 0; mf < 4; ++mf)
#pragma unroll
      for (int nf = 0; nf < NF; ++nf)
        acc[mf][nf] = __builtin_amdgcn_mfma_f32_16x16x32_bf16(a[mf], b[nf], acc[mf][nf], 0, 0, 0);
  }

#pragma unroll
  for (int nf = 0; nf < NF; ++nf) {
    int col = cbase + nf * 16 + lrow;
    float bv = bias ? bias[col] : 0.f;
#pragma unroll
    for (int mf = 0; mf < 4; ++mf) {
      int growb = row0 + rbase + mf * 16 + (lane >> 4) * 4;
#pragma unroll
      for (int r = 0; r < 4; ++r) {
        int grow = growb + r;
        if (grow < M) {
          float val = acc[mf][nf][r] + bv;
          if constexpr (BF16OUT)
            ((ushort*)Yv)[(size_t)grow * NCOL + col] = f2bf(val);
          else
            ((float*)Yv)[(size_t)grow * NCOL + col] = val;
        }
      }
    }
  }
}

// rowptr/cursor (nbS blocks) | GEMM1 pair from xbf: Pp = x@WA+bA -> Abf, Pq = x@WB+bB -> Qbf
__global__ __launch_bounds__(256) void k_p4(Params p) {
  const int bid = blockIdx.x, tid = threadIdx.x;
  if (bid < p.nbS) {
    int i = bid * 256 + tid;
    if (i < p.N) {
      int inc = p.incl[i] + p.bsums[bid];
      p.rowptr[i + 1] = inc;
      p.cursor[i] = inc - p.cnt[i];
    }
    if (i == 0) p.rowptr[0] = 0;
    return;
  }
  int job = bid - p.nbS;
  if (job < p.nbT) gemm_tile<128, true>(p.xbf, p.WAt, p.bA, p.Abf, p.N, job);
  else gemm_tile<128, true>(p.xbf, p.WBt, p.bB, p.Qbf, p.N, job - p.nbT);
}

__global__ __launch_bounds__(256) void k_gemm2(Params p) {
  int job = blockIdx.y * p.nbT + blockIdx.x;
  if (job < p.nbT) gemm_tile<128, true>(p.Dbf, p.Wlt, nullptr, p.Abf, p.N, job);
  else gemm_tile<128, true>(p.Dbf, p.Wrt, nullptr, p.Qbf, p.N, job - p.nbT);
}

__global__ __launch_bounds__(256) void k_gout(Params p) {
  gemm_tile<64, false>(p.Dbf, p.Wlint, p.b_lin, p.out, p.N, blockIdx.x);
}

// ================= gather/LN (R4 body: wave per node, 4 edges/iter, unconditional load) =================

__device__ __forceinline__ void gather_mean(const ushort* __restrict__ Pm, const int* __restrict__ rowptr,
                                            const int* __restrict__ srclist, int w, int lane, float* a) {
  const uint4* Pv = (const uint4*)Pm;
  int fl = lane & 15, g4 = lane >> 4;
  int beg = rowptr[w], end = rowptr[w + 1];
  for (int base = beg; base < end; base += 64) {
    int m = end - base;
    if (m > 64) m = 64;
    int sidx = (lane < m) ? srclist[base + lane] : 0;
    for (int i = 0; i < m; i += 4) {
      int j = i + g4;
      int s = __shfl(sidx, j, 64);
      uint4 u = Pv[(size_t)s * 16 + fl];
      if (j < m) {
        a[0] += bflo(u.x); a[1] += bfhi(u.x);
        a[2] += bflo(u.y); a[3] += bfhi(u.y);
        a[4] += bflo(u.z); a[5] += bfhi(u.z);
        a[6] += bflo(u.w); a[7] += bfhi(u.w);
      }
    }
  }
#pragma unroll
  for (int k = 0; k < 8; ++k) {
    a[k] += __shfl_xor(a[k], 16, 64);
    a[k] += __shfl_xor(a[k], 32, 64);
  }
  float inv = 1.f / fmaxf((float)(end - beg), 1.f);
#pragma unroll
  for (int k = 0; k < 8; ++k) a[k] *= inv;
}

__device__ __forceinline__ void ln_relu8(const float* h, const float* __restrict__ gamma,
                                         const float* __restrict__ beta, int fl, float* o) {
  float sum = 0.f;
#pragma unroll
  for (int k = 0; k < 8; ++k) sum += h[k];
#pragma unroll
  for (int off = 1; off < 16; off <<= 1) sum += __shfl_xor(sum, off, 64);
  float mu = sum * (1.f / 128.f);
  float s2 = 0.f;
#pragma unroll
  for (int k = 0; k < 8; ++k) { float d = h[k] - mu; s2 += d * d; }
#pragma unroll
  for (int off = 1; off < 16; off <<= 1) s2 += __shfl_xor(s2, off, 64);
  float scale = rsqrtf(s2 * (1.f / 128.f) + LN_EPS);
  float4 g0 = *(const float4*)(gamma + fl * 8);
  float4 g1 = *(const float4*)(gamma + fl * 8 + 4);
  float4 b0 = *(const float4*)(beta + fl * 8);
  float4 b1 = *(const float4*)(beta + fl * 8 + 4);
  float gg[8] = {g0.x, g0.y, g0.z, g0.w, g1.x, g1.y, g1.z, g1.w};
  float bb[8] = {b0.x, b0.y, b0.z, b0.w, b1.x, b1.y, b1.z, b1.w};
#pragma unroll
  for (int k = 0; k < 8; ++k) o[k] = fmaxf((h[k] - mu) * scale * gg[k] + bb[k], 0.f);
}

__device__ __forceinline__ uint4 pack8(const float* v) {
  uint4 u;
  u.x = pk2(v[0], v[1]); u.y = pk2(v[2], v[3]);
  u.z = pk2(v[4], v[5]); u.w = pk2(v[6], v[7]);
  return u;
}

// agg1: h1 = mean(Pp)+Pq+b_l -> H1 (bf16); r = relu(LN(h1)) -> Dbf (bf16)
__global__ __launch_bounds__(256) void k_agg1(Params p) {
  int w = (blockIdx.x * 256 + threadIdx.x) >> 6;
  int lane = threadIdx.x & 63;
  if (w >= p.N) return;
  int fl = lane & 15;
  float a[8] = {0.f, 0.f, 0.f, 0.f, 0.f, 0.f, 0.f, 0.f};
  gather_mean(p.Abf, p.rowptr, p.srclist, w, lane, a);
  uint4 qv = ((const uint4*)p.Qbf)[(size_t)w * 16 + fl];
  float4 bl0 = *(const float4*)(p.b_l + fl * 8);
  float4 bl1 = *(const float4*)(p.b_l + fl * 8 + 4);
  float q[8] = {bflo(qv.x), bfhi(qv.x), bflo(qv.y), bfhi(qv.y), bflo(qv.z), bfhi(qv.z), bflo(qv.w), bfhi(qv.w)};
  float bl[8] = {bl0.x, bl0.y, bl0.z, bl0.w, bl1.x, bl1.y, bl1.z, bl1.w};
  float h[8];
#pragma unroll
  for (int k = 0; k < 8; ++k) h[k] = a[k] + q[k] + bl[k];
  float r[8];
  ln_relu8(h, p.gamma, p.beta, fl, r);
  if (lane < 16) {
    ((uint4*)p.H1)[(size_t)w * 16 + fl] = pack8(h);
    ((uint4*)p.Dbf)[(size_t)w * 16 + fl] = pack8(r);
  }
}

// agg2: o = relu(LN(mean(U)+V+b_l+h1)) -> Dbf (bf16)
__global__ __launch_bounds__(256) void k_agg2(Params p) {
  int w = (blockIdx.x * 256 + threadIdx.x) >> 6;
  int lane = threadIdx.x & 63;
  if (w >= p.N) return;
  int fl = lane & 15;
  float a[8] = {0.f, 0.f, 0.f, 0.f, 0.f, 0.f, 0.f, 0.f};
  gather_mean(p.Abf, p.rowptr, p.srclist, w, lane, a);
  uint4 vv = ((const uint4*)p.Qbf)[(size_t)w * 16 + fl];
  uint4 hv = ((const uint4*)p.H1)[(size_t)w * 16 + fl];
  float4 bl0 = *(const float4*)(p.b_l + fl * 8);
  float4 bl1 = *(const float4*)(p.b_l + fl * 8 + 4);
  float vf[8] = {bflo(vv.x), bfhi(vv.x), bflo(vv.y), bfhi(vv.y), bflo(vv.z), bfhi(vv.z), bflo(vv.w), bfhi(vv.w)};
  float hf[8] = {bflo(hv.x), bfhi(hv.x), bflo(hv.y), bfhi(hv.y), bflo(hv.z), bfhi(hv.z), bflo(hv.w), bfhi(hv.w)};
  float bl[8] = {bl0.x, bl0.y, bl0.z, bl0.w, bl1.x, bl1.y, bl1.z, bl1.w};
  float h[8];
#pragma unroll
  for (int k = 0; k < 8; ++k) h[k] = a[k] + vf[k] + bl[k] + hf[k];
  float o[8];
  ln_relu8(h, p.gamma, p.beta, fl, o);
  if (lane < 16) ((uint4*)p.Dbf)[(size_t)w * 16 + fl] = pack8(o);
}

// ================= launch =================

extern "C" void kernel_launch(void* const* d_in, const int* in_sizes, int n_in,
                              void* d_out, int out_size, void* d_ws, size_t ws_size,
                              hipStream_t stream) {
  Params p;
  p.x = (const float*)d_in[0];
  p.ei = (const int*)d_in[1];
  // d_in[2] = edge_attr: unused by the reference
  p.W_ne = (const float*)d_in[3];
  p.b_ne = (const float*)d_in[4];
  p.W_l = (const float*)d_in[5];
  p.b_l = (const float*)d_in[6];
  p.W_r = (const float*)d_in[7];
  p.gamma = (const float*)d_in[8];
  p.beta = (const float*)d_in[9];
  p.W_lin = (const float*)d_in[10];
  p.b_lin = (const float*)d_in[11];
  p.out = (float*)d_out;

  p.N = in_sizes[0] / 128;
  p.E = in_sizes[1] / 2;
  p.nbS = (p.N + 255) / 256;
  p.nbT = (p.N + 127) / 128;   // 128-row GEMM tiles

  char* w = (char*)d_ws;
  const size_t S2 = (size_t)p.N * 128 * sizeof(ushort);
  p.Abf = (ushort*)w;    w += S2;
  p.Qbf = (ushort*)w;    w += S2;
  p.H1 = (ushort*)w;     w += S2;
  p.Dbf = (ushort*)w;    w += S2;
  p.xbf = (ushort*)w;    w += S2;
  p.WAt = (ushort*)w;    w += 128 * 128 * sizeof(ushort);
  p.WBt = (ushort*)w;    w += 128 * 128 * sizeof(ushort);
  p.Wlt = (ushort*)w;    w += 128 * 128 * sizeof(ushort);
  p.Wrt = (ushort*)w;    w += 128 * 128 * sizeof(ushort);
  p.Wlint = (ushort*)w;  w += 64 * 128 * sizeof(ushort);
  p.bA = (float*)w;      w += 128 * sizeof(float);
  p.bB = (float*)w;      w += 128 * sizeof(float);
  p.cnt = (int*)w;       w += (size_t)p.N * sizeof(int);
  p.incl = (int*)w;      w += (size_t)p.N * sizeof(int);
  p.rowptr = (int*)w;    w += ((size_t)p.N + 4) * sizeof(int);
  p.cursor = (int*)w;    w += (size_t)p.N * sizeof(int);
  p.bsums = (int*)w;     w += 1024 * sizeof(int);
  p.srclist = (int*)w;

  const int nbE = (p.E + 255) / 256;
  const int nbW = ((p.N * 64) + 255) / 256;

  hipMemsetAsync(p.cnt, 0, (size_t)p.N * sizeof(int), stream);
  k_hist<<<nbE, 256, 0, stream>>>(p);
  k_p2<<<p.nbS + 129 + 1024, 256, 0, stream>>>(p);
  k_scan2<<<1, 256, 0, stream>>>(p);
  k_p4<<<p.nbS + 2 * p.nbT, 256, 0, stream>>>(p);
  k_fill<<<nbE, 256, 0, stream>>>(p);
  k_agg1<<<nbW, 256, 0, stream>>>(p);
  k_gemm2<<<dim3(p.nbT, 2), 256, 0, stream>>>(p);
  k_agg2<<<nbW, 256, 0, stream>>>(p);
  k_gout<<<p.nbT, 256, 0, stream>>>(p);
}

// Round 9
// 241.622 us; speedup vs baseline: 5.4786x; 1.0402x over previous
//
#include <hip/hip_runtime.h>

typedef __attribute__((ext_vector_type(8))) short bf16x8;
typedef __attribute__((ext_vector_type(4))) float f32x4;

constexpr float LN_EPS = 1e-5f;

__device__ inline ushort f2bf(float f) {
  uint u = __float_as_uint(f);
  u += 0x7FFF + ((u >> 16) & 1);   // round-to-nearest-even
  return (ushort)(u >> 16);
}
__device__ inline float bflo(uint u) { return __uint_as_float(u << 16); }
__device__ inline float bfhi(uint u) { return __uint_as_float(u & 0xFFFF0000u); }
__device__ inline uint pk2(float lo, float hi) { return (uint)f2bf(lo) | ((uint)f2bf(hi) << 16); }

struct Params {
  const float* x; const int* ei;
  const float *W_ne, *b_ne, *W_l, *b_l, *W_r, *gamma, *beta, *W_lin, *b_lin;
  float* out;
  ushort *Abf, *Qbf, *H1, *Dbf, *xbf, *WAt, *WBt, *Wlt, *Wrt, *Wlint;
  float *bA, *bB;
  int *cnt, *incl, *rowptr, *cursor, *bsums, *srclist;
  int N, E, nbS, nbT;
};

// ================= CSR + prep =================

__global__ __launch_bounds__(256) void k_hist(Params p) {
  int e = blockIdx.x * 256 + threadIdx.x;
  if (e < p.E) atomicAdd(&p.cnt[p.ei[p.E + e]], 1);
}

// scan1 (nbS blocks) | WA/WB/bias prep (129 blocks) | x-cast + weight transpose-casts (rest, grid-stride)
__global__ __launch_bounds__(256) void k_p2(Params p) {
  __shared__ int sh[256];
  const int tid = threadIdx.x, bid = blockIdx.x;
  if (bid < p.nbS) {
    int i = bid * 256 + tid;
    int v = (i < p.N) ? p.cnt[i] : 0;
    sh[tid] = v;
    __syncthreads();
    for (int off = 1; off < 256; off <<= 1) {
      int t = (tid >= off) ? sh[tid - off] : 0;
      __syncthreads();
      sh[tid] += t;
      __syncthreads();
    }
    if (i < p.N) p.incl[i] = sh[tid];
    if (tid == 255) p.bsums[bid] = sh[255];
  } else if (bid < p.nbS + 129) {
    int blk = bid - p.nbS;
    float* srow = (float*)sh;
    const float* src = (blk < 128) ? (p.W_ne + blk * 128) : p.b_ne;
    if (tid < 128) srow[tid] = src[tid];
    __syncthreads();
    int col = tid & 127;
    const float* Wx = (tid < 128) ? p.W_l : p.W_r;
    float acc = 0.f;
#pragma unroll 8
    for (int k = 0; k < 128; ++k) acc = fmaf(srow[k], Wx[k * 128 + col], acc);
    if (blk < 128) {
      ushort* dst = (tid < 128) ? p.WAt : p.WBt;
      dst[col * 128 + blk] = f2bf(acc);
    } else {
      float* dst = (tid < 128) ? p.bA : p.bB;
      dst[col] = acc;
    }
  } else {
    const int nx16 = p.N * 16;
    const int total = nx16 + 16384 + 16384 + 8192;
    const int i0 = (bid - (p.nbS + 129)) * 256 + tid;
    const int st = (gridDim.x - (p.nbS + 129)) * 256;
    const float4* xin = (const float4*)p.x;
    uint4* xo = (uint4*)p.xbf;
    for (int idx = i0; idx < total; idx += st) {
      if (idx < nx16) {
        float4 a = xin[2 * (size_t)idx], b = xin[2 * (size_t)idx + 1];
        uint4 v;
        v.x = pk2(a.x, a.y); v.y = pk2(a.z, a.w);
        v.z = pk2(b.x, b.y); v.w = pk2(b.z, b.w);
        xo[idx] = v;
        continue;
      }
      int t = idx - nx16;
      if (t < 16384) { p.Wlt[(t & 127) * 128 + (t >> 7)] = f2bf(p.W_l[t]); continue; }
      t -= 16384;
      if (t < 16384) { p.Wrt[(t & 127) * 128 + (t >> 7)] = f2bf(p.W_r[t]); continue; }
      t -= 16384;
      p.Wlint[(t & 63) * 128 + (t >> 6)] = f2bf(p.W_lin[t]);
    }
  }
}

__global__ __launch_bounds__(256) void k_scan2(Params p) {
  __shared__ int sh[256];
  const int tid = threadIdx.x;
  int v = (tid < p.nbS) ? p.bsums[tid] : 0;
  sh[tid] = v;
  __syncthreads();
  for (int off = 1; off < 256; off <<= 1) {
    int t = (tid >= off) ? sh[tid - off] : 0;
    __syncthreads();
    sh[tid] += t;
    __syncthreads();
  }
  if (tid < p.nbS) p.bsums[tid] = sh[tid] - v;  // exclusive
}

__global__ __launch_bounds__(256) void k_fill(Params p) {
  int e = blockIdx.x * 256 + threadIdx.x;
  if (e >= p.E) return;
  int s = p.ei[e], d = p.ei[p.E + e];
  int pos = atomicAdd(&p.cursor[d], 1);
  p.srclist[pos] = s;
}

// ================= no-LDS MFMA GEMM: 128 rows x NCOL, 4 waves 2x2 =================
// X bf16 [M][128]; Wt bf16 [NCOL][128] transposed.

template <int NCOL, bool BF16OUT>
__device__ __forceinline__ void gemm_tile(const ushort* __restrict__ X, const ushort* __restrict__ Wt,
                                          const float* __restrict__ bias, void* __restrict__ Yv,
                                          int M, int tile) {
  constexpr int NF = NCOL / 32;
  const int tid = threadIdx.x;
  const int wave = tid >> 6, lane = tid & 63;
  const int rbase = (wave >> 1) * 64;
  const int cbase = (wave & 1) * (NCOL / 2);
  const int lrow = lane & 15;
  const int lkb = (lane >> 4) * 8;
  const int row0 = tile * 128;

  size_t rIdx[4];
#pragma unroll
  for (int mf = 0; mf < 4; ++mf) {
    int r = row0 + rbase + mf * 16 + lrow;
    rIdx[mf] = (size_t)((r < M) ? r : (M - 1));
  }

  f32x4 acc[4][NF];
#pragma unroll
  for (int mf = 0; mf < 4; ++mf)
#pragma unroll
    for (int nf = 0; nf < NF; ++nf) acc[mf][nf] = (f32x4){0.f, 0.f, 0.f, 0.f};

#pragma unroll
  for (int ks = 0; ks < 4; ++ks) {
    bf16x8 a[4], b[NF];
#pragma unroll
    for (int mf = 0; mf < 4; ++mf)
      a[mf] = *(const bf16x8*)(X + rIdx[mf] * 128 + ks * 32 + lkb);
#pragma unroll
    for (int nf = 0; nf < NF; ++nf)
      b[nf] = *(const bf16x8*)(Wt + (size_t)(cbase + nf * 16 + lrow) * 128 + ks * 32 + lkb);
#pragma unroll
    for (int mf = 0; mf < 4; ++mf)
#pragma unroll
      for (int nf = 0; nf < NF; ++nf)
        acc[mf][nf] = __builtin_amdgcn_mfma_f32_16x16x32_bf16(a[mf], b[nf], acc[mf][nf], 0, 0, 0);
  }

#pragma unroll
  for (int nf = 0; nf < NF; ++nf) {
    int col = cbase + nf * 16 + lrow;
    float bv = bias ? bias[col] : 0.f;
#pragma unroll
    for (int mf = 0; mf < 4; ++mf) {
      int growb = row0 + rbase + mf * 16 + (lane >> 4) * 4;
#pragma unroll
      for (int r = 0; r < 4; ++r) {
        int grow = growb + r;
        if (grow < M) {
          float val = acc[mf][nf][r] + bv;
          if constexpr (BF16OUT)
            ((ushort*)Yv)[(size_t)grow * NCOL + col] = f2bf(val);
          else
            ((float*)Yv)[(size_t)grow * NCOL + col] = val;
        }
      }
    }
  }
}

// rowptr/cursor (nbS blocks) | GEMM1 pair from xbf
__global__ __launch_bounds__(256) void k_p4(Params p) {
  const int bid = blockIdx.x, tid = threadIdx.x;
  if (bid < p.nbS) {
    int i = bid * 256 + tid;
    if (i < p.N) {
      int inc = p.incl[i] + p.bsums[bid];
      p.rowptr[i + 1] = inc;
      p.cursor[i] = inc - p.cnt[i];
    }
    if (i == 0) p.rowptr[0] = 0;
    return;
  }
  int job = bid - p.nbS;
  if (job < p.nbT) gemm_tile<128, true>(p.xbf, p.WAt, p.bA, p.Abf, p.N, job);
  else gemm_tile<128, true>(p.xbf, p.WBt, p.bB, p.Qbf, p.N, job - p.nbT);
}

__global__ __launch_bounds__(256) void k_gemm2(Params p) {
  int job = blockIdx.y * p.nbT + blockIdx.x;
  if (job < p.nbT) gemm_tile<128, true>(p.Dbf, p.Wlt, nullptr, p.Abf, p.N, job);
  else gemm_tile<128, true>(p.Dbf, p.Wrt, nullptr, p.Qbf, p.N, job - p.nbT);
}

__global__ __launch_bounds__(256) void k_gout(Params p) {
  gemm_tile<64, false>(p.Dbf, p.Wlint, p.b_lin, p.out, p.N, blockIdx.x);
}

// ================= gather/LN: wave per node, 16 edges/iter (4 unconditional loads in flight) =================

__device__ __forceinline__ void acc8(uint4 u, float* a) {
  a[0] += bflo(u.x); a[1] += bfhi(u.x);
  a[2] += bflo(u.y); a[3] += bfhi(u.y);
  a[4] += bflo(u.z); a[5] += bfhi(u.z);
  a[6] += bflo(u.w); a[7] += bfhi(u.w);
}

__device__ __forceinline__ void gather_mean(const ushort* __restrict__ Pm, const int* __restrict__ rowptr,
                                            const int* __restrict__ srclist, int w, int lane, float* a) {
  const uint4* Pv = (const uint4*)Pm;
  int fl = lane & 15, g4 = lane >> 4;
  int beg = rowptr[w], end = rowptr[w + 1];
  for (int base = beg; base < end; base += 64) {
    int m = end - base;
    if (m > 64) m = 64;
    // lanes >= m read srclist slot 0 of this chunk? -> use 0 (valid row); loads stay unconditional
    int sidx = (lane < m) ? srclist[base + lane] : 0;
    for (int i = 0; i < m; i += 16) {
      int j0 = i + g4, j1 = j0 + 4, j2 = j0 + 8, j3 = j0 + 12;
      int s0 = __shfl(sidx, j0 & 63, 64);
      int s1 = __shfl(sidx, j1 & 63, 64);
      int s2 = __shfl(sidx, j2 & 63, 64);
      int s3 = __shfl(sidx, j3 & 63, 64);
      uint4 u0 = Pv[(size_t)s0 * 16 + fl];   // all loads unconditional: indices always valid
      uint4 u1 = Pv[(size_t)s1 * 16 + fl];
      uint4 u2 = Pv[(size_t)s2 * 16 + fl];
      uint4 u3 = Pv[(size_t)s3 * 16 + fl];
      if (j0 < m) acc8(u0, a);
      if (j1 < m) acc8(u1, a);
      if (j2 < m) acc8(u2, a);
      if (j3 < m) acc8(u3, a);
    }
  }
#pragma unroll
  for (int k = 0; k < 8; ++k) {
    a[k] += __shfl_xor(a[k], 16, 64);
    a[k] += __shfl_xor(a[k], 32, 64);
  }
  float inv = 1.f / fmaxf((float)(end - beg), 1.f);
#pragma unroll
  for (int k = 0; k < 8; ++k) a[k] *= inv;
}

__device__ __forceinline__ void ln_relu8(const float* h, const float* __restrict__ gamma,
                                         const float* __restrict__ beta, int fl, float* o) {
  float sum = 0.f;
#pragma unroll
  for (int k = 0; k < 8; ++k) sum += h[k];
#pragma unroll
  for (int off = 1; off < 16; off <<= 1) sum += __shfl_xor(sum, off, 64);
  float mu = sum * (1.f / 128.f);
  float s2 = 0.f;
#pragma unroll
  for (int k = 0; k < 8; ++k) { float d = h[k] - mu; s2 += d * d; }
#pragma unroll
  for (int off = 1; off < 16; off <<= 1) s2 += __shfl_xor(s2, off, 64);
  float scale = rsqrtf(s2 * (1.f / 128.f) + LN_EPS);
  float4 g0 = *(const float4*)(gamma + fl * 8);
  float4 g1 = *(const float4*)(gamma + fl * 8 + 4);
  float4 b0 = *(const float4*)(beta + fl * 8);
  float4 b1 = *(const float4*)(beta + fl * 8 + 4);
  float gg[8] = {g0.x, g0.y, g0.z, g0.w, g1.x, g1.y, g1.z, g1.w};
  float bb[8] = {b0.x, b0.y, b0.z, b0.w, b1.x, b1.y, b1.z, b1.w};
#pragma unroll
  for (int k = 0; k < 8; ++k) o[k] = fmaxf((h[k] - mu) * scale * gg[k] + bb[k], 0.f);
}

__device__ __forceinline__ uint4 pack8(const float* v) {
  uint4 u;
  u.x = pk2(v[0], v[1]); u.y = pk2(v[2], v[3]);
  u.z = pk2(v[4], v[5]); u.w = pk2(v[6], v[7]);
  return u;
}

// agg1: h1 = mean(Pp)+Pq+b_l -> H1 (bf16); r = relu(LN(h1)) -> Dbf (bf16)
__global__ __launch_bounds__(256) void k_agg1(Params p) {
  int w = (blockIdx.x * 256 + threadIdx.x) >> 6;
  int lane = threadIdx.x & 63;
  if (w >= p.N) return;
  int fl = lane & 15;
  float a[8] = {0.f, 0.f, 0.f, 0.f, 0.f, 0.f, 0.f, 0.f};
  gather_mean(p.Abf, p.rowptr, p.srclist, w, lane, a);
  uint4 qv = ((const uint4*)p.Qbf)[(size_t)w * 16 + fl];
  float4 bl0 = *(const float4*)(p.b_l + fl * 8);
  float4 bl1 = *(const float4*)(p.b_l + fl * 8 + 4);
  float q[8] = {bflo(qv.x), bfhi(qv.x), bflo(qv.y), bfhi(qv.y), bflo(qv.z), bfhi(qv.z), bflo(qv.w), bfhi(qv.w)};
  float bl[8] = {bl0.x, bl0.y, bl0.z, bl0.w, bl1.x, bl1.y, bl1.z, bl1.w};
  float h[8];
#pragma unroll
  for (int k = 0; k < 8; ++k) h[k] = a[k] + q[k] + bl[k];
  float r[8];
  ln_relu8(h, p.gamma, p.beta, fl, r);
  if (lane < 16) {
    ((uint4*)p.H1)[(size_t)w * 16 + fl] = pack8(h);
    ((uint4*)p.Dbf)[(size_t)w * 16 + fl] = pack8(r);
  }
}

// agg2: o = relu(LN(mean(U)+V+b_l+h1)) -> Dbf (bf16)
__global__ __launch_bounds__(256) void k_agg2(Params p) {
  int w = (blockIdx.x * 256 + threadIdx.x) >> 6;
  int lane = threadIdx.x & 63;
  if (w >= p.N) return;
  int fl = lane & 15;
  float a[8] = {0.f, 0.f, 0.f, 0.f, 0.f, 0.f, 0.f, 0.f};
  gather_mean(p.Abf, p.rowptr, p.srclist, w, lane, a);
  uint4 vv = ((const uint4*)p.Qbf)[(size_t)w * 16 + fl];
  uint4 hv = ((const uint4*)p.H1)[(size_t)w * 16 + fl];
  float4 bl0 = *(const float4*)(p.b_l + fl * 8);
  float4 bl1 = *(const float4*)(p.b_l + fl * 8 + 4);
  float vf[8] = {bflo(vv.x), bfhi(vv.x), bflo(vv.y), bfhi(vv.y), bflo(vv.z), bfhi(vv.z), bflo(vv.w), bfhi(vv.w)};
  float hf[8] = {bflo(hv.x), bfhi(hv.x), bflo(hv.y), bfhi(hv.y), bflo(hv.z), bfhi(hv.z), bflo(hv.w), bfhi(hv.w)};
  float bl[8] = {bl0.x, bl0.y, bl0.z, bl0.w, bl1.x, bl1.y, bl1.z, bl1.w};
  float h[8];
#pragma unroll
  for (int k = 0; k < 8; ++k) h[k] = a[k] + vf[k] + bl[k] + hf[k];
  float o[8];
  ln_relu8(h, p.gamma, p.beta, fl, o);
  if (lane < 16) ((uint4*)p.Dbf)[(size_t)w * 16 + fl] = pack8(o);
}

// ================= launch =================

extern "C" void kernel_launch(void* const* d_in, const int* in_sizes, int n_in,
                              void* d_out, int out_size, void* d_ws, size_t ws_size,
                              hipStream_t stream) {
  Params p;
  p.x = (const float*)d_in[0];
  p.ei = (const int*)d_in[1];
  // d_in[2] = edge_attr: unused by the reference
  p.W_ne = (const float*)d_in[3];
  p.b_ne = (const float*)d_in[4];
  p.W_l = (const float*)d_in[5];
  p.b_l = (const float*)d_in[6];
  p.W_r = (const float*)d_in[7];
  p.gamma = (const float*)d_in[8];
  p.beta = (const float*)d_in[9];
  p.W_lin = (const float*)d_in[10];
  p.b_lin = (const float*)d_in[11];
  p.out = (float*)d_out;

  p.N = in_sizes[0] / 128;
  p.E = in_sizes[1] / 2;
  p.nbS = (p.N + 255) / 256;
  p.nbT = (p.N + 127) / 128;   // 128-row GEMM tiles

  char* w = (char*)d_ws;
  const size_t S2 = (size_t)p.N * 128 * sizeof(ushort);
  p.Abf = (ushort*)w;    w += S2;
  p.Qbf = (ushort*)w;    w += S2;
  p.H1 = (ushort*)w;     w += S2;
  p.Dbf = (ushort*)w;    w += S2;
  p.xbf = (ushort*)w;    w += S2;
  p.WAt = (ushort*)w;    w += 128 * 128 * sizeof(ushort);
  p.WBt = (ushort*)w;    w += 128 * 128 * sizeof(ushort);
  p.Wlt = (ushort*)w;    w += 128 * 128 * sizeof(ushort);
  p.Wrt = (ushort*)w;    w += 128 * 128 * sizeof(ushort);
  p.Wlint = (ushort*)w;  w += 64 * 128 * sizeof(ushort);
  p.bA = (float*)w;      w += 128 * sizeof(float);
  p.bB = (float*)w;      w += 128 * sizeof(float);
  p.cnt = (int*)w;       w += (size_t)p.N * sizeof(int);
  p.incl = (int*)w;      w += (size_t)p.N * sizeof(int);
  p.rowptr = (int*)w;    w += ((size_t)p.N + 4) * sizeof(int);
  p.cursor = (int*)w;    w += (size_t)p.N * sizeof(int);
  p.bsums = (int*)w;     w += 1024 * sizeof(int);
  p.srclist = (int*)w;

  const int nbE = (p.E + 255) / 256;
  const int nbW = ((p.N * 64) + 255) / 256;

  hipMemsetAsync(p.cnt, 0, (size_t)p.N * sizeof(int), stream);
  k_hist<<<nbE, 256, 0, stream>>>(p);
  k_p2<<<p.nbS + 129 + 1024, 256, 0, stream>>>(p);
  k_scan2<<<1, 256, 0, stream>>>(p);
  k_p4<<<p.nbS + 2 * p.nbT, 256, 0, stream>>>(p);
  k_fill<<<nbE, 256, 0, stream>>>(p);
  k_agg1<<<nbW, 256, 0, stream>>>(p);
  k_gemm2<<<dim3(p.nbT, 2), 256, 0, stream>>>(p);
  k_agg2<<<nbW, 256, 0, stream>>>(p);
  k_gout<<<p.nbT, 256, 0, stream>>>(p);
}

// Round 10
// 224.836 us; speedup vs baseline: 5.8876x; 1.0747x over previous
//
#include <hip/hip_runtime.h>

typedef __attribute__((ext_vector_type(8))) short bf16x8;
typedef __attribute__((ext_vector_type(4))) float f32x4;

constexpr float LN_EPS = 1e-5f;

__device__ inline ushort f2bf(float f) {
  uint u = __float_as_uint(f);
  u += 0x7FFF + ((u >> 16) & 1);   // round-to-nearest-even
  return (ushort)(u >> 16);
}
__device__ inline float bflo(uint u) { return __uint_as_float(u << 16); }
__device__ inline float bfhi(uint u) { return __uint_as_float(u & 0xFFFF0000u); }
__device__ inline uint pk2(float lo, float hi) { return (uint)f2bf(lo) | ((uint)f2bf(hi) << 16); }

struct Params {
  const float* x; const int* ei;
  const float *W_ne, *b_ne, *W_l, *b_l, *W_r, *gamma, *beta, *W_lin, *b_lin;
  float* out;
  ushort *Qbf, *H1, *Dbf, *xbf, *WAt, *WBt, *Wlt, *Wrt, *Wlint;
  signed char* Aq;          // gathered operand, int8 [N][128]
  float* Ascale;            // per-row scale [N]
  float *bA, *bB;
  int *cnt, *incl, *rowptr, *cursor, *bsums, *srclist;
  int N, E, nbS, nbT;
};

// ================= CSR + prep =================

__global__ __launch_bounds__(256) void k_hist(Params p) {
  int e = blockIdx.x * 256 + threadIdx.x;
  if (e < p.E) atomicAdd(&p.cnt[p.ei[p.E + e]], 1);
}

// scan1 (nbS blocks) | WA/WB/bias prep (129 blocks) | x-cast + weight transpose-casts (rest)
__global__ __launch_bounds__(256) void k_p2(Params p) {
  __shared__ int sh[256];
  const int tid = threadIdx.x, bid = blockIdx.x;
  if (bid < p.nbS) {
    int i = bid * 256 + tid;
    int v = (i < p.N) ? p.cnt[i] : 0;
    sh[tid] = v;
    __syncthreads();
    for (int off = 1; off < 256; off <<= 1) {
      int t = (tid >= off) ? sh[tid - off] : 0;
      __syncthreads();
      sh[tid] += t;
      __syncthreads();
    }
    if (i < p.N) p.incl[i] = sh[tid];
    if (tid == 255) p.bsums[bid] = sh[255];
  } else if (bid < p.nbS + 129) {
    int blk = bid - p.nbS;
    float* srow = (float*)sh;
    const float* src = (blk < 128) ? (p.W_ne + blk * 128) : p.b_ne;
    if (tid < 128) srow[tid] = src[tid];
    __syncthreads();
    int col = tid & 127;
    const float* Wx = (tid < 128) ? p.W_l : p.W_r;
    float acc = 0.f;
#pragma unroll 8
    for (int k = 0; k < 128; ++k) acc = fmaf(srow[k], Wx[k * 128 + col], acc);
    if (blk < 128) {
      ushort* dst = (tid < 128) ? p.WAt : p.WBt;
      dst[col * 128 + blk] = f2bf(acc);
    } else {
      float* dst = (tid < 128) ? p.bA : p.bB;
      dst[col] = acc;
    }
  } else {
    const int nx16 = p.N * 16;
    const int total = nx16 + 16384 + 16384 + 8192;
    const int i0 = (bid - (p.nbS + 129)) * 256 + tid;
    const int st = (gridDim.x - (p.nbS + 129)) * 256;
    const float4* xin = (const float4*)p.x;
    uint4* xo = (uint4*)p.xbf;
    for (int idx = i0; idx < total; idx += st) {
      if (idx < nx16) {
        float4 a = xin[2 * (size_t)idx], b = xin[2 * (size_t)idx + 1];
        uint4 v;
        v.x = pk2(a.x, a.y); v.y = pk2(a.z, a.w);
        v.z = pk2(b.x, b.y); v.w = pk2(b.z, b.w);
        xo[idx] = v;
        continue;
      }
      int t = idx - nx16;
      if (t < 16384) { p.Wlt[(t & 127) * 128 + (t >> 7)] = f2bf(p.W_l[t]); continue; }
      t -= 16384;
      if (t < 16384) { p.Wrt[(t & 127) * 128 + (t >> 7)] = f2bf(p.W_r[t]); continue; }
      t -= 16384;
      p.Wlint[(t & 63) * 128 + (t >> 6)] = f2bf(p.W_lin[t]);
    }
  }
}

__global__ __launch_bounds__(256) void k_fill(Params p) {
  int e = blockIdx.x * 256 + threadIdx.x;
  if (e >= p.E) return;
  int s = p.ei[e], d = p.ei[p.E + e];
  int pos = atomicAdd(&p.cursor[d], 1);
  p.srclist[pos] = s;
}

// ================= no-LDS MFMA GEMM: 128 rows x NCOL, 4 waves 2x2 =================
// X bf16 [M][128]; Wt bf16 [NCOL][128]. OMODE: 0=f32, 1=bf16, 2=int8+per-row-scale.

template <int NCOL, int OMODE>
__device__ __forceinline__ void gemm_tile(const ushort* __restrict__ X, const ushort* __restrict__ Wt,
                                          const float* __restrict__ bias, void* __restrict__ Yv,
                                          float* __restrict__ Yscale, int M, int tile, char* ldsraw) {
  constexpr int NF = NCOL / 32;
  const int tid = threadIdx.x;
  const int wave = tid >> 6, lane = tid & 63;
  const int rbase = (wave >> 1) * 64;
  const int cbase = (wave & 1) * (NCOL / 2);
  const int lrow = lane & 15;
  const int lkb = (lane >> 4) * 8;
  const int row0 = tile * 128;

  size_t rIdx[4];
#pragma unroll
  for (int mf = 0; mf < 4; ++mf) {
    int r = row0 + rbase + mf * 16 + lrow;
    rIdx[mf] = (size_t)((r < M) ? r : (M - 1));
  }

  f32x4 acc[4][NF];
#pragma unroll
  for (int mf = 0; mf < 4; ++mf)
#pragma unroll
    for (int nf = 0; nf < NF; ++nf) acc[mf][nf] = (f32x4){0.f, 0.f, 0.f, 0.f};

#pragma unroll
  for (int ks = 0; ks < 4; ++ks) {
    bf16x8 a[4], b[NF];
#pragma unroll
    for (int mf = 0; mf < 4; ++mf)
      a[mf] = *(const bf16x8*)(X + rIdx[mf] * 128 + ks * 32 + lkb);
#pragma unroll
    for (int nf = 0; nf < NF; ++nf)
      b[nf] = *(const bf16x8*)(Wt + (size_t)(cbase + nf * 16 + lrow) * 128 + ks * 32 + lkb);
#pragma unroll
    for (int mf = 0; mf < 4; ++mf)
#pragma unroll
      for (int nf = 0; nf < NF; ++nf)
        acc[mf][nf] = __builtin_amdgcn_mfma_f32_16x16x32_bf16(a[mf], b[nf], acc[mf][nf], 0, 0, 0);
  }

  // fold bias into acc
  if (bias) {
#pragma unroll
    for (int nf = 0; nf < NF; ++nf) {
      float bv = bias[cbase + nf * 16 + lrow];
#pragma unroll
      for (int mf = 0; mf < 4; ++mf)
#pragma unroll
        for (int r = 0; r < 4; ++r) acc[mf][nf][r] += bv;
    }
  }

  if constexpr (OMODE == 2) {
    float (*rmaxh)[2] = (float(*)[2])ldsraw;            // [128][2]
    signed char (*qt)[128] = (signed char(*)[128])(ldsraw + 1024);  // [128][128]
#pragma unroll
    for (int mf = 0; mf < 4; ++mf)
#pragma unroll
      for (int r = 0; r < 4; ++r) {
        float m = 0.f;
#pragma unroll
        for (int nf = 0; nf < NF; ++nf) m = fmaxf(m, fabsf(acc[mf][nf][r]));
#pragma unroll
        for (int off = 1; off < 16; off <<= 1) m = fmaxf(m, __shfl_xor(m, off, 64));
        int lr = rbase + mf * 16 + (lane >> 4) * 4 + r;
        if (lrow == 0) rmaxh[lr][wave & 1] = m;
      }
    __syncthreads();
#pragma unroll
    for (int mf = 0; mf < 4; ++mf)
#pragma unroll
      for (int r = 0; r < 4; ++r) {
        int lr = rbase + mf * 16 + (lane >> 4) * 4 + r;
        float mx = fmaxf(rmaxh[lr][0], rmaxh[lr][1]);
        float inv = (mx > 0.f) ? 127.f / mx : 0.f;
#pragma unroll
        for (int nf = 0; nf < NF; ++nf)
          qt[lr][cbase + nf * 16 + lrow] = (signed char)__float2int_rn(acc[mf][nf][r] * inv);
      }
    __syncthreads();
    signed char* Yq = (signed char*)Yv;
    for (int idx = tid; idx < 1024; idx += 256) {
      int lr = idx >> 3, co = (idx & 7) * 16;
      int grow = row0 + lr;
      if (grow < M) *(uint4*)(Yq + (size_t)grow * 128 + co) = *(const uint4*)&qt[lr][co];
    }
    if (tid < 128) {
      int grow = row0 + tid;
      if (grow < M) Yscale[grow] = fmaxf(rmaxh[tid][0], rmaxh[tid][1]) * (1.f / 127.f);
    }
    return;
  }

#pragma unroll
  for (int nf = 0; nf < NF; ++nf) {
    int col = cbase + nf * 16 + lrow;
#pragma unroll
    for (int mf = 0; mf < 4; ++mf) {
      int growb = row0 + rbase + mf * 16 + (lane >> 4) * 4;
#pragma unroll
      for (int r = 0; r < 4; ++r) {
        int grow = growb + r;
        if (grow < M) {
          float val = acc[mf][nf][r];
          if constexpr (OMODE == 1)
            ((ushort*)Yv)[(size_t)grow * NCOL + col] = f2bf(val);
          else
            ((float*)Yv)[(size_t)grow * NCOL + col] = val;
        }
      }
    }
  }
}

// rowptr/cursor with folded bsums-prefix (nbS blocks) | GEMM1 pair from xbf
__global__ __launch_bounds__(256) void k_p4(Params p) {
  __shared__ __align__(16) char qlds[1024 + 16384];
  const int bid = blockIdx.x, tid = threadIdx.x;
  if (bid < p.nbS) {
    int* ss = (int*)qlds;
    int v = (tid < bid) ? p.bsums[tid] : 0;
    ss[tid] = v;
    __syncthreads();
    for (int off = 128; off > 0; off >>= 1) {
      if (tid < off) ss[tid] += ss[tid + off];
      __syncthreads();
    }
    int prefix = ss[0];
    int i = bid * 256 + tid;
    if (i < p.N) {
      int inc = p.incl[i] + prefix;
      p.rowptr[i + 1] = inc;
      p.cursor[i] = inc - p.cnt[i];
    }
    if (i == 0) p.rowptr[0] = 0;
    return;
  }
  int job = bid - p.nbS;
  if (job < p.nbT) gemm_tile<128, 2>(p.xbf, p.WAt, p.bA, p.Aq, p.Ascale, p.N, job, qlds);
  else gemm_tile<128, 1>(p.xbf, p.WBt, p.bB, p.Qbf, nullptr, p.N, job - p.nbT, qlds);
}

__global__ __launch_bounds__(256) void k_gemm2(Params p) {
  __shared__ __align__(16) char qlds[1024 + 16384];
  int job = blockIdx.y * p.nbT + blockIdx.x;
  if (job < p.nbT) gemm_tile<128, 2>(p.Dbf, p.Wlt, nullptr, p.Aq, p.Ascale, p.N, job, qlds);
  else gemm_tile<128, 1>(p.Dbf, p.Wrt, nullptr, p.Qbf, nullptr, p.N, job - p.nbT, qlds);
}

__global__ __launch_bounds__(256) void k_gout(Params p) {
  gemm_tile<64, 0>(p.Dbf, p.Wlint, p.b_lin, p.out, nullptr, p.N, blockIdx.x, nullptr);
}

// ================= gather/LN: wave per node, 16 edges/iter, int8 rows + per-row scale =================

__device__ __forceinline__ void acc8q(uint2 u, float sc, float* a) {
  a[0] = fmaf((float)(int)(signed char)(u.x & 0xFF), sc, a[0]);
  a[1] = fmaf((float)(int)(signed char)((u.x >> 8) & 0xFF), sc, a[1]);
  a[2] = fmaf((float)(int)(signed char)((u.x >> 16) & 0xFF), sc, a[2]);
  a[3] = fmaf((float)(int)(signed char)(u.x >> 24), sc, a[3]);
  a[4] = fmaf((float)(int)(signed char)(u.y & 0xFF), sc, a[4]);
  a[5] = fmaf((float)(int)(signed char)((u.y >> 8) & 0xFF), sc, a[5]);
  a[6] = fmaf((float)(int)(signed char)((u.y >> 16) & 0xFF), sc, a[6]);
  a[7] = fmaf((float)(int)(signed char)(u.y >> 24), sc, a[7]);
}

__device__ __forceinline__ void gather_mean(const signed char* __restrict__ Pq, const float* __restrict__ Psc,
                                            const int* __restrict__ rowptr, const int* __restrict__ srclist,
                                            int w, int lane, float* a) {
  int fl = lane & 15, g4 = lane >> 4;
  int beg = rowptr[w], end = rowptr[w + 1];
  for (int base = beg; base < end; base += 64) {
    int m = end - base;
    if (m > 64) m = 64;
    int sidx = (lane < m) ? srclist[base + lane] : 0;
    for (int i = 0; i < m; i += 16) {
      int j0 = i + g4, j1 = j0 + 4, j2 = j0 + 8, j3 = j0 + 12;
      int s0 = __shfl(sidx, j0 & 63, 64);
      int s1 = __shfl(sidx, j1 & 63, 64);
      int s2 = __shfl(sidx, j2 & 63, 64);
      int s3 = __shfl(sidx, j3 & 63, 64);
      float c0 = Psc[s0], c1 = Psc[s1], c2 = Psc[s2], c3 = Psc[s3];
      uint2 u0 = *(const uint2*)(Pq + (size_t)s0 * 128 + fl * 8);   // unconditional: indices valid
      uint2 u1 = *(const uint2*)(Pq + (size_t)s1 * 128 + fl * 8);
      uint2 u2 = *(const uint2*)(Pq + (size_t)s2 * 128 + fl * 8);
      uint2 u3 = *(const uint2*)(Pq + (size_t)s3 * 128 + fl * 8);
      if (j0 < m) acc8q(u0, c0, a);
      if (j1 < m) acc8q(u1, c1, a);
      if (j2 < m) acc8q(u2, c2, a);
      if (j3 < m) acc8q(u3, c3, a);
    }
  }
#pragma unroll
  for (int k = 0; k < 8; ++k) {
    a[k] += __shfl_xor(a[k], 16, 64);
    a[k] += __shfl_xor(a[k], 32, 64);
  }
  float inv = 1.f / fmaxf((float)(end - beg), 1.f);
#pragma unroll
  for (int k = 0; k < 8; ++k) a[k] *= inv;
}

__device__ __forceinline__ void ln_relu8(const float* h, const float* __restrict__ gamma,
                                         const float* __restrict__ beta, int fl, float* o) {
  float sum = 0.f;
#pragma unroll
  for (int k = 0; k < 8; ++k) sum += h[k];
#pragma unroll
  for (int off = 1; off < 16; off <<= 1) sum += __shfl_xor(sum, off, 64);
  float mu = sum * (1.f / 128.f);
  float s2 = 0.f;
#pragma unroll
  for (int k = 0; k < 8; ++k) { float d = h[k] - mu; s2 += d * d; }
#pragma unroll
  for (int off = 1; off < 16; off <<= 1) s2 += __shfl_xor(s2, off, 64);
  float scale = rsqrtf(s2 * (1.f / 128.f) + LN_EPS);
  float4 g0 = *(const float4*)(gamma + fl * 8);
  float4 g1 = *(const float4*)(gamma + fl * 8 + 4);
  float4 b0 = *(const float4*)(beta + fl * 8);
  float4 b1 = *(const float4*)(beta + fl * 8 + 4);
  float gg[8] = {g0.x, g0.y, g0.z, g0.w, g1.x, g1.y, g1.z, g1.w};
  float bb[8] = {b0.x, b0.y, b0.z, b0.w, b1.x, b1.y, b1.z, b1.w};
#pragma unroll
  for (int k = 0; k < 8; ++k) o[k] = fmaxf((h[k] - mu) * scale * gg[k] + bb[k], 0.f);
}

__device__ __forceinline__ uint4 pack8(const float* v) {
  uint4 u;
  u.x = pk2(v[0], v[1]); u.y = pk2(v[2], v[3]);
  u.z = pk2(v[4], v[5]); u.w = pk2(v[6], v[7]);
  return u;
}

// agg1: h1 = mean(Pq)+Qbf+b_l -> H1 (bf16); r = relu(LN(h1)) -> Dbf (bf16)
__global__ __launch_bounds__(256) void k_agg1(Params p) {
  int w = (blockIdx.x * 256 + threadIdx.x) >> 6;
  int lane = threadIdx.x & 63;
  if (w >= p.N) return;
  int fl = lane & 15;
  float a[8] = {0.f, 0.f, 0.f, 0.f, 0.f, 0.f, 0.f, 0.f};
  gather_mean(p.Aq, p.Ascale, p.rowptr, p.srclist, w, lane, a);
  uint4 qv = ((const uint4*)p.Qbf)[(size_t)w * 16 + fl];
  float4 bl0 = *(const float4*)(p.b_l + fl * 8);
  float4 bl1 = *(const float4*)(p.b_l + fl * 8 + 4);
  float q[8] = {bflo(qv.x), bfhi(qv.x), bflo(qv.y), bfhi(qv.y), bflo(qv.z), bfhi(qv.z), bflo(qv.w), bfhi(qv.w)};
  float bl[8] = {bl0.x, bl0.y, bl0.z, bl0.w, bl1.x, bl1.y, bl1.z, bl1.w};
  float h[8];
#pragma unroll
  for (int k = 0; k < 8; ++k) h[k] = a[k] + q[k] + bl[k];
  float r[8];
  ln_relu8(h, p.gamma, p.beta, fl, r);
  if (lane < 16) {
    ((uint4*)p.H1)[(size_t)w * 16 + fl] = pack8(h);
    ((uint4*)p.Dbf)[(size_t)w * 16 + fl] = pack8(r);
  }
}

// agg2: o = relu(LN(mean(Uq)+V+b_l+h1)) -> Dbf (bf16)
__global__ __launch_bounds__(256) void k_agg2(Params p) {
  int w = (blockIdx.x * 256 + threadIdx.x) >> 6;
  int lane = threadIdx.x & 63;
  if (w >= p.N) return;
  int fl = lane & 15;
  float a[8] = {0.f, 0.f, 0.f, 0.f, 0.f, 0.f, 0.f, 0.f};
  gather_mean(p.Aq, p.Ascale, p.rowptr, p.srclist, w, lane, a);
  uint4 vv = ((const uint4*)p.Qbf)[(size_t)w * 16 + fl];
  uint4 hv = ((const uint4*)p.H1)[(size_t)w * 16 + fl];
  float4 bl0 = *(const float4*)(p.b_l + fl * 8);
  float4 bl1 = *(const float4*)(p.b_l + fl * 8 + 4);
  float vf[8] = {bflo(vv.x), bfhi(vv.x), bflo(vv.y), bfhi(vv.y), bflo(vv.z), bfhi(vv.z), bflo(vv.w), bfhi(vv.w)};
  float hf[8] = {bflo(hv.x), bfhi(hv.x), bflo(hv.y), bfhi(hv.y), bflo(hv.z), bfhi(hv.z), bflo(hv.w), bfhi(hv.w)};
  float bl[8] = {bl0.x, bl0.y, bl0.z, bl0.w, bl1.x, bl1.y, bl1.z, bl1.w};
  float h[8];
#pragma unroll
  for (int k = 0; k < 8; ++k) h[k] = a[k] + vf[k] + bl[k] + hf[k];
  float o[8];
  ln_relu8(h, p.gamma, p.beta, fl, o);
  if (lane < 16) ((uint4*)p.Dbf)[(size_t)w * 16 + fl] = pack8(o);
}

// ================= launch =================

extern "C" void kernel_launch(void* const* d_in, const int* in_sizes, int n_in,
                              void* d_out, int out_size, void* d_ws, size_t ws_size,
                              hipStream_t stream) {
  Params p;
  p.x = (const float*)d_in[0];
  p.ei = (const int*)d_in[1];
  // d_in[2] = edge_attr: unused by the reference
  p.W_ne = (const float*)d_in[3];
  p.b_ne = (const float*)d_in[4];
  p.W_l = (const float*)d_in[5];
  p.b_l = (const float*)d_in[6];
  p.W_r = (const float*)d_in[7];
  p.gamma = (const float*)d_in[8];
  p.beta = (const float*)d_in[9];
  p.W_lin = (const float*)d_in[10];
  p.b_lin = (const float*)d_in[11];
  p.out = (float*)d_out;

  p.N = in_sizes[0] / 128;
  p.E = in_sizes[1] / 2;
  p.nbS = (p.N + 255) / 256;
  p.nbT = (p.N + 127) / 128;

  char* w = (char*)d_ws;
  const size_t S2 = (size_t)p.N * 128 * sizeof(ushort);
  p.Qbf = (ushort*)w;    w += S2;
  p.H1 = (ushort*)w;     w += S2;
  p.Dbf = (ushort*)w;    w += S2;
  p.xbf = (ushort*)w;    w += S2;
  p.Aq = (signed char*)w;  w += (size_t)p.N * 128;
  p.Ascale = (float*)w;  w += (size_t)p.N * sizeof(float);
  p.WAt = (ushort*)w;    w += 128 * 128 * sizeof(ushort);
  p.WBt = (ushort*)w;    w += 128 * 128 * sizeof(ushort);
  p.Wlt = (ushort*)w;    w += 128 * 128 * sizeof(ushort);
  p.Wrt = (ushort*)w;    w += 128 * 128 * sizeof(ushort);
  p.Wlint = (ushort*)w;  w += 64 * 128 * sizeof(ushort);
  p.bA = (float*)w;      w += 128 * sizeof(float);
  p.bB = (float*)w;      w += 128 * sizeof(float);
  p.cnt = (int*)w;       w += (size_t)p.N * sizeof(int);
  p.incl = (int*)w;      w += (size_t)p.N * sizeof(int);
  p.rowptr = (int*)w;    w += ((size_t)p.N + 4) * sizeof(int);
  p.cursor = (int*)w;    w += (size_t)p.N * sizeof(int);
  p.bsums = (int*)w;     w += 1024 * sizeof(int);
  p.srclist = (int*)w;

  const int nbE = (p.E + 255) / 256;
  const int nbW = ((p.N * 64) + 255) / 256;

  hipMemsetAsync(p.cnt, 0, (size_t)p.N * sizeof(int), stream);
  k_hist<<<nbE, 256, 0, stream>>>(p);
  k_p2<<<p.nbS + 129 + 1024, 256, 0, stream>>>(p);
  k_p4<<<p.nbS + 2 * p.nbT, 256, 0, stream>>>(p);
  k_fill<<<nbE, 256, 0, stream>>>(p);
  k_agg1<<<nbW, 256, 0, stream>>>(p);
  k_gemm2<<<dim3(p.nbT, 2), 256, 0, stream>>>(p);
  k_agg2<<<nbW, 256, 0, stream>>>(p);
  k_gout<<<p.nbT, 256, 0, stream>>>(p);
}